// Round 1
// baseline (1701.621 us; speedup 1.0000x reference)
//
#include <hip/hip_runtime.h>
#include <math.h>

#define CIN 64
#define CCOND 80
#define NLAYERS 4
#define HOP 256
#define CLEN 128
#define ILEN 4096
#define OLEN 32768
#define LROWS 24576   // rows of kk per layer = 64*128*3

__device__ __forceinline__ float lrelu(float x, float s) { return x >= 0.f ? x : s * x; }

// ---------------- prep: weight transposes for coalesced lane access ----------------
__global__ void prep_kernel(const float* __restrict__ up_w, const float* __restrict__ kin_w,
                            const float* __restrict__ kres_w, const float* __restrict__ conv_w,
                            float* __restrict__ w_up_t, float* __restrict__ kin_t,
                            float* __restrict__ kres_t, float* __restrict__ wct) {
  int i = blockIdx.x * 256 + threadIdx.x;
  if (i < 16 * 64 * 64) {              // w_up_t[a][ci][co] <- up_w[ci][co][a]
    int a = i >> 12, r = i & 4095, ci = r >> 6, co = r & 63;
    w_up_t[i] = up_w[(ci * 64 + co) * 16 + a];
  }
  if (i < 80 * 5 * 64) {               // kin_t[cc][t][ch] <- kin_w[ch][cc][t]
    int ch = i & 63, r = i >> 6, t = r % 5, cc = r / 5;
    kin_t[i] = kin_w[(ch * 80 + cc) * 5 + t];
  }
  if (i < 6 * 64 * 3 * 64) {           // kres_t[j][ci][k][ch] <- kres_w[j][ch][ci][k]
    int ch = i & 63, r = i >> 6, k = r % 3; r /= 3; int ci = r & 63, j = r >> 6;
    kres_t[i] = kres_w[((j * 64 + ch) * 64 + ci) * 3 + k];
  }
  if (i < 4 * 64 * 3 * 64) {           // wct[l][ci][k][co] <- conv_w[l][co][ci][k]
    int co = i & 63, r = i >> 6, k = r % 3; r /= 3; int ci = r & 63, l = r >> 6;
    wct[i] = conv_w[((l * 64 + co) * 64 + ci) * 3 + k];
  }
}

// ---------------- kernel predictor head: conv5 (80->64) + lrelu(0.1) ----------------
__global__ void kp_head(const float* __restrict__ c, const float* __restrict__ kin_t,
                        const float* __restrict__ kin_b, float* __restrict__ hkp) {
  int blk = blockIdx.x, b = blk >> 7, l = blk & 127;
  int ch = threadIdx.x;
  float acc = kin_b[ch];
  for (int cc = 0; cc < 80; cc++) {
    const float* cp = c + (b * 80 + cc) * 128;
    #pragma unroll
    for (int t = 0; t < 5; t++) {
      int li = l + t - 2;
      if (li >= 0 && li < 128) acc += cp[li] * kin_t[(cc * 5 + t) * 64 + ch];
    }
  }
  hkp[(b * 64 + ch) * 128 + l] = lrelu(acc, 0.1f);
}

// ---------------- residual conv3 (64->64) + lrelu(0.1) ----------------
__global__ void kp_res(const float* __restrict__ rin, const float* __restrict__ kres_t,
                       const float* __restrict__ kres_b, int j, float* __restrict__ rout) {
  __shared__ float rs[192];
  int blk = blockIdx.x, b = blk >> 7, l = blk & 127;
  int ch = threadIdx.x;
  for (int idx = ch; idx < 192; idx += 64) {
    int ci = idx / 3, k = idx % 3, li = l + k - 1;
    rs[idx] = (li >= 0 && li < 128) ? rin[(b * 64 + ci) * 128 + li] : 0.f;
  }
  __syncthreads();
  float acc = kres_b[j * 64 + ch];
  const float* wt = kres_t + j * 12288 + ch;
  for (int idx = 0; idx < 192; idx++) acc += rs[idx] * wt[idx * 64];
  rout[(b * 64 + ch) * 128 + l] = lrelu(acc, 0.1f);
}

__global__ void add2(const float* __restrict__ a, const float* __restrict__ b,
                     float* __restrict__ o, int n) {
  int i = blockIdx.x * 256 + threadIdx.x;
  if (i < n) o[i] = a[i] + b[i];
}

// ---------------- bias predictor conv3 (64->512) ----------------
__global__ void kb_conv(const float* __restrict__ hsum, const float* __restrict__ kb_w,
                        const float* __restrict__ kb_b, float* __restrict__ bias_all) {
  int i = blockIdx.x * 256 + threadIdx.x;   // over 4*512*128
  int l = i & 127, r = (i >> 7) & 511, b = i >> 16;
  float acc = kb_b[r];
  const float* wp = kb_w + r * 192;
  const float* hp = hsum + b * 64 * 128;
  for (int hid = 0; hid < 64; hid++) {
    #pragma unroll
    for (int t = 0; t < 3; t++) {
      int li = l + t - 1;
      if (li >= 0 && li < 128) acc += hp[hid * 128 + li] * wp[hid * 3 + t];
    }
  }
  bias_all[i] = acc;
}

// ---------------- conv-transpose upsample x8 (with input lrelu 0.2) ----------------
__global__ void upsample(const float* __restrict__ x, const float* __restrict__ w_up_t,
                         const float* __restrict__ up_b, float* __restrict__ h) {
  int tid = threadIdx.x, co = tid & 63;
  int blk = blockIdx.x;                      // 32768 blocks
  int b = blk >> 13;
  int t = ((blk & 8191) << 2) | (tid >> 6);
  int kk0 = (11 - t) & 7;
  int s0 = (t + kk0 - 11) >> 3;              // exact multiple of 8
  float acc = up_b[co];
  const float* w0 = w_up_t + (15 - kk0) * 4096 + co;
  const float* w1 = w_up_t + (7 - kk0) * 4096 + co;
  const float* xb = x + b * 64 * ILEN;
  bool v0 = (s0 >= 0) && (s0 < ILEN);
  bool v1 = (s0 + 1 >= 0) && (s0 + 1 < ILEN);
  int s0c = v0 ? s0 : 0, s1c = v1 ? (s0 + 1) : 0;
  float m0 = v0 ? 1.f : 0.f, m1 = v1 ? 1.f : 0.f;
  #pragma unroll 8
  for (int ci = 0; ci < 64; ci++) {
    float x0 = lrelu(xb[ci * ILEN + s0c], 0.2f) * m0;
    float x1 = lrelu(xb[ci * ILEN + s1c], 0.2f) * m1;
    acc += x0 * w0[ci * 64] + x1 * w1[ci * 64];
  }
  h[(b * 64 + co) * OLEN + t] = acc;
}

// ---------------- kk GEMM: kern[col= b*128+l][row] = kk_w(layer) @ im2col(hsum) ----------------
__global__ void kk_gemm(const float* __restrict__ hsum, const float* __restrict__ kk_w,
                        const float* __restrict__ kk_b, int layer, float* __restrict__ kern) {
  __shared__ float As[64][68];   // [k][row]  (+4 pad)
  __shared__ float Bs[64][64];   // [k][col]
  int col0 = blockIdx.x * 64;    // 8 col tiles
  int row0 = blockIdx.y * 64;    // 384 row tiles
  int b = col0 >> 7, l0 = col0 & 127;
  int tid = threadIdx.x;
  int tr = tid & 15, tc = tid >> 4;
  int r0 = tr * 4, c0 = tc * 4;
  const float* Ap = kk_w + (size_t)(layer * LROWS + row0) * 192;
  const float* hp = hsum + b * 64 * 128;
  float acc[4][4];
  #pragma unroll
  for (int rr = 0; rr < 4; rr++) {
    float bv = kk_b[layer * LROWS + row0 + r0 + rr];
    #pragma unroll
    for (int cc = 0; cc < 4; cc++) acc[cc][rr] = bv;
  }
  for (int kc = 0; kc < 3; kc++) {
    for (int idx = tid; idx < 4096; idx += 256) {
      int rr = idx >> 6, kk = idx & 63;
      As[kk][rr] = Ap[rr * 192 + kc * 64 + kk];
    }
    for (int idx = tid; idx < 4096; idx += 256) {
      int kk = idx >> 6, cc = idx & 63;
      int kg = kc * 64 + kk, hid = kg / 3, t = kg % 3;
      int li = l0 + cc + t - 1;
      Bs[kk][cc] = (li >= 0 && li < 128) ? hp[hid * 128 + li] : 0.f;
    }
    __syncthreads();
    #pragma unroll 8
    for (int kk = 0; kk < 64; kk++) {
      float a[4], bb[4];
      #pragma unroll
      for (int u = 0; u < 4; u++) a[u] = As[kk][r0 + u];
      #pragma unroll
      for (int u = 0; u < 4; u++) bb[u] = Bs[kk][c0 + u];
      #pragma unroll
      for (int cc = 0; cc < 4; cc++)
        #pragma unroll
        for (int rr = 0; rr < 4; rr++) acc[cc][rr] += bb[cc] * a[rr];
    }
    __syncthreads();
  }
  #pragma unroll
  for (int cc = 0; cc < 4; cc++) {
    float* op = kern + (size_t)(col0 + c0 + cc) * LROWS + row0 + r0;
    #pragma unroll
    for (int rr = 0; rr < 4; rr++) op[rr] = acc[cc][rr];
  }
}

// ---------------- dilated conv3 (lrelu in, lrelu out) ----------------
template <int DIL>
__launch_bounds__(256, 2)
__global__ void conv_layer(const float* __restrict__ h, const float* __restrict__ wct,
                           const float* __restrict__ conv_b, int layer, float* __restrict__ y) {
  constexpr int W = 128 + 2 * DIL;
  constexpr int WP = (W + 3) & ~3;
  __shared__ float hs[32][WP];
  __shared__ float Ws[32 * 3 * 64];
  int blk = blockIdx.x, b = blk >> 8, tt = blk & 255;
  int t0 = tt * 128;
  int tid = threadIdx.x;
  int tc = tid & 7, ts = tid >> 3;
  int c0 = tc * 8, s0 = ts * 4;
  float acc[8][4];
  #pragma unroll
  for (int r = 0; r < 8; r++) {
    float bv = conv_b[layer * 64 + c0 + r];
    #pragma unroll
    for (int j = 0; j < 4; j++) acc[r][j] = bv;
  }
  const float* hb = h + (size_t)b * 64 * OLEN;
  for (int half = 0; half < 2; half++) {
    __syncthreads();
    for (int idx = tid; idx < 32 * W; idx += 256) {
      int cil = idx / W, u = idx % W;
      int t = t0 - DIL + u;
      hs[cil][u] = (t >= 0 && t < OLEN) ? lrelu(hb[(half * 32 + cil) * OLEN + t], 0.2f) : 0.f;
    }
    const float* wp = wct + (layer * 64 + half * 32) * 192;
    for (int idx = tid; idx < 6144; idx += 256) Ws[idx] = wp[idx];
    __syncthreads();
    for (int cil = 0; cil < 32; cil++) {
      #pragma unroll
      for (int k = 0; k < 3; k++) {
        float a[8], xv[4];
        const float* wq = &Ws[(cil * 3 + k) * 64 + c0];
        #pragma unroll
        for (int u = 0; u < 8; u++) a[u] = wq[u];
        const float* xq = &hs[cil][s0 + k * DIL];
        #pragma unroll
        for (int j = 0; j < 4; j++) xv[j] = xq[j];
        #pragma unroll
        for (int r = 0; r < 8; r++)
          #pragma unroll
          for (int j = 0; j < 4; j++) acc[r][j] += a[r] * xv[j];
      }
    }
  }
  float* yb = y + (size_t)b * 64 * OLEN;
  #pragma unroll
  for (int r = 0; r < 8; r++) {
    float* yp = yb + (c0 + r) * OLEN + t0 + s0;
    #pragma unroll
    for (int j = 0; j < 4; j++) yp[j] = lrelu(acc[r][j], 0.2f);
  }
}

// ---------------- LVC + sigmoid*tanh gate, h += ----------------
__launch_bounds__(256, 2)
__global__ void lvc_gate(const float* __restrict__ y, const float* __restrict__ kern,
                         const float* __restrict__ bias_all, int layer, float* __restrict__ h) {
  __shared__ float ys[64][132];       // y[b][ci][t0-1 .. t0+128]
  __shared__ float Ks[16 * 3 * 128];  // [ci_loc][k][co]
  int blk = blockIdx.x;
  int sh = blk & 1, l = (blk >> 1) & 127, b = blk >> 8;
  int t0 = l * 256 + sh * 128;
  int tid = threadIdx.x;
  const float* yb = y + (size_t)b * 64 * OLEN;
  for (int idx = tid; idx < 64 * 130; idx += 256) {
    int ci = idx / 130, j = idx % 130;
    int t = t0 - 1 + j;
    ys[ci][j] = (t >= 0 && t < OLEN) ? yb[ci * OLEN + t] : 0.f;
  }
  int tc = tid & 15, ts = tid >> 4;
  int c0 = tc * 4, s0 = ts * 8;
  float acc[8][8];
  #pragma unroll
  for (int r = 0; r < 4; r++) {
    float blo = bias_all[(b * 512 + layer * 128 + c0 + r) * 128 + l];
    float bhi = bias_all[(b * 512 + layer * 128 + c0 + 64 + r) * 128 + l];
    #pragma unroll
    for (int j = 0; j < 8; j++) { acc[r][j] = blo; acc[r + 4][j] = bhi; }
  }
  const float* kb_ = kern + (size_t)(b * 128 + l) * LROWS;
  for (int chunk = 0; chunk < 4; chunk++) {
    __syncthreads();
    for (int idx = tid; idx < 6144; idx += 256) {
      int ci_loc = idx / 384, rem = idx % 384, co = rem / 3, k = rem % 3;
      Ks[(ci_loc * 3 + k) * 128 + co] = kb_[chunk * 6144 + idx];
    }
    __syncthreads();
    for (int ci_loc = 0; ci_loc < 16; ci_loc++) {
      int ci = chunk * 16 + ci_loc;
      float xv[12];
      #pragma unroll
      for (int u = 0; u < 12; u++) xv[u] = ys[ci][s0 + u];   // xv[10..11] unused
      #pragma unroll
      for (int k = 0; k < 3; k++) {
        float alo[4], ahi[4];
        const float* kp = &Ks[(ci_loc * 3 + k) * 128];
        #pragma unroll
        for (int u = 0; u < 4; u++) alo[u] = kp[c0 + u];
        #pragma unroll
        for (int u = 0; u < 4; u++) ahi[u] = kp[c0 + 64 + u];
        #pragma unroll
        for (int r = 0; r < 4; r++)
          #pragma unroll
          for (int j = 0; j < 8; j++) {
            acc[r][j]     += alo[r] * xv[j + k];
            acc[r + 4][j] += ahi[r] * xv[j + k];
          }
      }
    }
  }
  float* hb = h + (size_t)b * 64 * OLEN;
  #pragma unroll
  for (int r = 0; r < 4; r++) {
    float* hp = hb + (c0 + r) * OLEN + t0 + s0;
    #pragma unroll
    for (int j = 0; j < 8; j++) {
      float sg = 1.f / (1.f + expf(-acc[r][j]));
      float th = tanhf(acc[r + 4][j]);
      hp[j] += sg * th;
    }
  }
}

extern "C" void kernel_launch(void* const* d_in, const int* in_sizes, int n_in,
                              void* d_out, int out_size, void* d_ws, size_t ws_size,
                              hipStream_t stream) {
  const float* x      = (const float*)d_in[0];
  const float* c      = (const float*)d_in[1];
  const float* up_w   = (const float*)d_in[2];
  const float* up_b   = (const float*)d_in[3];
  const float* kin_w  = (const float*)d_in[4];
  const float* kin_b  = (const float*)d_in[5];
  const float* kres_w = (const float*)d_in[6];
  const float* kres_b = (const float*)d_in[7];
  const float* kk_w   = (const float*)d_in[8];
  const float* kk_b   = (const float*)d_in[9];
  const float* kb_w   = (const float*)d_in[10];
  const float* kb_b   = (const float*)d_in[11];
  const float* conv_w = (const float*)d_in[12];
  const float* conv_b = (const float*)d_in[13];
  float* h = (float*)d_out;

  float* ws = (float*)d_ws;
  float* w_up_t   = ws; ws += 16 * 64 * 64;
  float* kin_t    = ws; ws += 80 * 5 * 64;
  float* kres_t   = ws; ws += 6 * 64 * 3 * 64;
  float* wct      = ws; ws += 4 * 64 * 3 * 64;
  float* hkp      = ws; ws += 4 * 64 * 128;
  float* ra       = ws; ws += 4 * 64 * 128;
  float* rb       = ws; ws += 4 * 64 * 128;
  float* hsum     = ws; ws += 4 * 64 * 128;
  float* bias_all = ws; ws += 4 * 512 * 128;
  float* ybuf     = ws; ws += (size_t)4 * 64 * OLEN;
  float* kern     = ws; ws += (size_t)512 * LROWS;

  prep_kernel<<<288, 256, 0, stream>>>(up_w, kin_w, kres_w, conv_w, w_up_t, kin_t, kres_t, wct);
  kp_head<<<512, 64, 0, stream>>>(c, kin_t, kin_b, hkp);
  const float* rin = hkp;
  float* rout = ra;
  for (int j = 0; j < 6; j++) {
    kp_res<<<512, 64, 0, stream>>>(rin, kres_t, kres_b, j, rout);
    rin = rout;
    rout = (rout == ra) ? rb : ra;
  }
  add2<<<128, 256, 0, stream>>>(hkp, rin, hsum, 32768);
  kb_conv<<<1024, 256, 0, stream>>>(hsum, kb_w, kb_b, bias_all);
  upsample<<<32768, 256, 0, stream>>>(x, w_up_t, up_b, h);

  for (int layer = 0; layer < NLAYERS; layer++) {
    kk_gemm<<<dim3(8, 384), 256, 0, stream>>>(hsum, kk_w, kk_b, layer, kern);
    switch (layer) {
      case 0: conv_layer<1><<<1024, 256, 0, stream>>>(h, wct, conv_b, layer, ybuf); break;
      case 1: conv_layer<3><<<1024, 256, 0, stream>>>(h, wct, conv_b, layer, ybuf); break;
      case 2: conv_layer<9><<<1024, 256, 0, stream>>>(h, wct, conv_b, layer, ybuf); break;
      case 3: conv_layer<27><<<1024, 256, 0, stream>>>(h, wct, conv_b, layer, ybuf); break;
    }
    lvc_gate<<<1024, 256, 0, stream>>>(ybuf, kern, bias_all, layer, h);
  }
}

// Round 2
// 1200.733 us; speedup vs baseline: 1.4172x; 1.4172x over previous
//
#include <hip/hip_runtime.h>
#include <math.h>

#define CIN 64
#define NLAYERS 4
#define HOP 256
#define ILEN 4096
#define OLEN 32768
#define LROWS 24576   // rows of kk per layer = 64*128*3

typedef unsigned int uint;
typedef unsigned short ushort;
typedef __attribute__((ext_vector_type(8))) short bh8;
typedef __attribute__((ext_vector_type(4))) float f4;
typedef __attribute__((ext_vector_type(8))) unsigned short us8;
typedef __attribute__((ext_vector_type(4))) unsigned short us4;

__device__ __forceinline__ float lrelu(float x, float s) { return x >= 0.f ? x : s * x; }

__device__ __forceinline__ ushort f2b(float f) {       // fp32 -> bf16 (RNE)
  uint u = __float_as_uint(f);
  u = u + 0x7fff + ((u >> 16) & 1);
  return (ushort)(u >> 16);
}
__device__ __forceinline__ float b2f(ushort u) {
  return __uint_as_float(((uint)u) << 16);
}
__device__ __forceinline__ f4 mfma16(bh8 a, bh8 b, f4 c) {
  return __builtin_amdgcn_mfma_f32_16x16x32_bf16(a, b, c, 0, 0, 0);
}

// ---------------- prep: weight transposes ----------------
__global__ void prep_kernel(const float* __restrict__ kin_w, const float* __restrict__ kres_w,
                            const float* __restrict__ conv_w,
                            float* __restrict__ kin_t, float* __restrict__ kres_t,
                            float* __restrict__ wct) {
  int i = blockIdx.x * 256 + threadIdx.x;
  if (i < 80 * 5 * 64) {               // kin_t[cc][t][ch] <- kin_w[ch][cc][t]
    int ch = i & 63, r = i >> 6, t = r % 5, cc = r / 5;
    kin_t[i] = kin_w[(ch * 80 + cc) * 5 + t];
  }
  if (i < 6 * 64 * 3 * 64) {           // kres_t[j][ci][k][ch] <- kres_w[j][ch][ci][k]
    int ch = i & 63, r = i >> 6, k = r % 3; r /= 3; int ci = r & 63, j = r >> 6;
    kres_t[i] = kres_w[((j * 64 + ch) * 64 + ci) * 3 + k];
  }
  if (i < 4 * 64 * 3 * 64) {           // wct[l][ci][k][co] <- conv_w[l][co][ci][k]
    int co = i & 63, r = i >> 6, k = r % 3; r /= 3; int ci = r & 63, l = r >> 6;
    wct[i] = conv_w[((l * 64 + co) * 64 + ci) * 3 + k];
  }
}

// A matrix for upsample MFMA: A3[m=co*8+ph][k=(u+1)*64+ci], u = input shift -1/0/+1
__global__ void prep_up_a(const float* __restrict__ up_w, ushort* __restrict__ A3) {
  int i = blockIdx.x * 256 + threadIdx.x;
  if (i >= 512 * 192) return;
  int k = i % 192, m = i / 192;
  int co = m >> 3, ph = m & 7;
  int u = k / 64 - 1, ci = k % 64;
  int kk0 = (11 - ph) & 7;
  int off = (ph < 4) ? -1 : 0;
  int tap = u - off;
  float v = 0.f;
  if (tap == 0 || tap == 1) {
    int a = 15 - kk0 - 8 * tap;
    v = up_w[(ci * 64 + co) * 16 + a];
  }
  A3[i] = f2b(v);
}

// xT[b][1+s][ci] = bf16(lrelu(x[b][ci][s])), rows 0 and 4097 zero-padded
__global__ void prep_xt(const float* __restrict__ x, ushort* __restrict__ xT) {
  __shared__ float ls[64][65];
  int blk = blockIdx.x, b = blk >> 6, st = blk & 63;
  int s0 = st * 64;
  int tid = threadIdx.x;
  int c2 = tid >> 6, s = tid & 63;
  #pragma unroll
  for (int r = 0; r < 16; r++) {
    int ci = r * 4 + c2;
    ls[ci][s] = lrelu(x[((size_t)b * 64 + ci) * ILEN + s0 + s], 0.2f);
  }
  __syncthreads();
  int ci = tid & 63, r2 = tid >> 6;
  #pragma unroll
  for (int r = 0; r < 16; r++) {
    int ss = r * 4 + r2;
    xT[((size_t)b * 4098 + 1 + s0 + ss) * 64 + ci] = f2b(ls[ci][ss]);
  }
  if (st == 0) {
    if (tid < 64) xT[((size_t)b * 4098) * 64 + tid] = 0;
    else if (tid < 128) xT[((size_t)b * 4098 + 4097) * 64 + (tid - 64)] = 0;
  }
}

// B matrix for kk GEMM (layer-invariant): Bim[col=b*128+l][k=hid*3+t] = hsum[b][hid][l+t-1]
__global__ void prep_bim(const float* __restrict__ hsum, ushort* __restrict__ Bim) {
  int i = blockIdx.x * 256 + threadIdx.x;
  if (i >= 4 * 128 * 192) return;
  int k = i % 192, l = (i / 192) & 127, b = i / (192 * 128);
  int hid = k / 3, t = k % 3, li = l + t - 1;
  float v = (li >= 0 && li < 128) ? hsum[(b * 64 + hid) * 128 + li] : 0.f;
  Bim[i] = f2b(v);
}

// ---------------- kernel predictor head: conv5 (80->64) + lrelu(0.1) ----------------
__global__ void kp_head(const float* __restrict__ c, const float* __restrict__ kin_t,
                        const float* __restrict__ kin_b, float* __restrict__ hkp) {
  int blk = blockIdx.x, b = blk >> 7, l = blk & 127;
  int ch = threadIdx.x;
  float acc = kin_b[ch];
  for (int cc = 0; cc < 80; cc++) {
    const float* cp = c + (b * 80 + cc) * 128;
    #pragma unroll
    for (int t = 0; t < 5; t++) {
      int li = l + t - 2;
      if (li >= 0 && li < 128) acc += cp[li] * kin_t[(cc * 5 + t) * 64 + ch];
    }
  }
  hkp[(b * 64 + ch) * 128 + l] = lrelu(acc, 0.1f);
}

// ---------------- residual conv3 (64->64) + lrelu(0.1) ----------------
__global__ void kp_res(const float* __restrict__ rin, const float* __restrict__ kres_t,
                       const float* __restrict__ kres_b, int j, float* __restrict__ rout) {
  __shared__ float rs[192];
  int blk = blockIdx.x, b = blk >> 7, l = blk & 127;
  int ch = threadIdx.x;
  for (int idx = ch; idx < 192; idx += 64) {
    int ci = idx / 3, k = idx % 3, li = l + k - 1;
    rs[idx] = (li >= 0 && li < 128) ? rin[(b * 64 + ci) * 128 + li] : 0.f;
  }
  __syncthreads();
  float acc = kres_b[j * 64 + ch];
  const float* wt = kres_t + j * 12288 + ch;
  for (int idx = 0; idx < 192; idx++) acc += rs[idx] * wt[idx * 64];
  rout[(b * 64 + ch) * 128 + l] = lrelu(acc, 0.1f);
}

__global__ void add2(const float* __restrict__ a, const float* __restrict__ b,
                     float* __restrict__ o, int n) {
  int i = blockIdx.x * 256 + threadIdx.x;
  if (i < n) o[i] = a[i] + b[i];
}

// ---------------- bias predictor conv3 (64->512) ----------------
__global__ void kb_conv(const float* __restrict__ hsum, const float* __restrict__ kb_w,
                        const float* __restrict__ kb_b, float* __restrict__ bias_all) {
  int i = blockIdx.x * 256 + threadIdx.x;   // over 4*512*128
  int l = i & 127, r = (i >> 7) & 511, b = i >> 16;
  float acc = kb_b[r];
  const float* wp = kb_w + r * 192;
  const float* hp = hsum + b * 64 * 128;
  for (int hid = 0; hid < 64; hid++) {
    #pragma unroll
    for (int t = 0; t < 3; t++) {
      int li = l + t - 1;
      if (li >= 0 && li < 128) acc += hp[hid * 128 + li] * wp[hid * 3 + t];
    }
  }
  bias_all[i] = acc;
}

// ---------------- upsample as MFMA GEMM: M=512 (co*8+ph), N=4096 (s), K=192 ----------------
#define UP_KP 200
__launch_bounds__(256, 2)
__global__ void upsample_mfma(const ushort* __restrict__ xT, const ushort* __restrict__ A3,
                              const float* __restrict__ up_b, float* __restrict__ h) {
  __shared__ ushort As[128 * UP_KP];   // 50 KB
  __shared__ ushort Bs[32 * UP_KP];    // 12.5 KB
  int s0 = blockIdx.x * 32;            // 128 s-tiles
  int m0 = blockIdx.y * 128;           // 4 co-tiles (16 co each)
  int b  = blockIdx.z;
  int tid = threadIdx.x;
  // stage A (512x192 bf16, L2-resident)
  {
    const ushort* src = A3 + (size_t)m0 * 192;
    for (int i = tid; i < 128 * 24; i += 256) {
      int m = i / 24, c8 = (i % 24) * 8;
      us8 v = *(const us8*)(src + (size_t)m * 192 + c8);
      *(us8*)(&As[m * UP_KP + c8]) = v;
    }
  }
  // stage B: Bs[n][(u)*64+ci] = xT[b][s0+n+u][ci]  (xT already +1 biased)
  for (int i = tid; i < 32 * 24; i += 256) {
    int n = i / 24, rr = i % 24, u = rr / 8, c8 = (rr % 8) * 8;
    us8 v = *(const us8*)(xT + ((size_t)b * 4098 + s0 + n + u) * 64 + c8);
    *(us8*)(&Bs[n * UP_KP + u * 64 + c8]) = v;
  }
  __syncthreads();
  int w = tid >> 6, lane = tid & 63, q = lane >> 4, ln = lane & 15;
  int wm = w * 32;
  f4 acc[2][2] = {};
  #pragma unroll
  for (int ks = 0; ks < 6; ks++) {
    int kb = ks * 32 + q * 8;
    bh8 a0 = *(const bh8*)(&As[(wm + ln) * UP_KP + kb]);
    bh8 a1 = *(const bh8*)(&As[(wm + 16 + ln) * UP_KP + kb]);
    bh8 b0 = *(const bh8*)(&Bs[ln * UP_KP + kb]);
    bh8 b1 = *(const bh8*)(&Bs[(16 + ln) * UP_KP + kb]);
    acc[0][0] = mfma16(a0, b0, acc[0][0]);
    acc[0][1] = mfma16(a0, b1, acc[0][1]);
    acc[1][0] = mfma16(a1, b0, acc[1][0]);
    acc[1][1] = mfma16(a1, b1, acc[1][1]);
  }
  #pragma unroll
  for (int mi = 0; mi < 2; mi++) {
    int mloc = wm + mi * 16 + q * 4;
    int co = (m0 + mloc) >> 3;
    int ph0 = mloc & 7;                 // = (q&1)*4
    float bias = up_b[co];
    #pragma unroll
    for (int ni = 0; ni < 2; ni++) {
      int n = s0 + ni * 16 + ln;
      f4 v = acc[mi][ni];
      float4 o = make_float4(v[0] + bias, v[1] + bias, v[2] + bias, v[3] + bias);
      *(float4*)(h + ((size_t)b * 64 + co) * OLEN + n * 8 + ph0) = o;
    }
  }
}

// ---------------- kk GEMM (MFMA): kern_bf16[col][row], M=24576, N=512, K=192 ----------------
#define KKP 104
__launch_bounds__(256, 2)
__global__ void kk_gemm_mfma(const float* __restrict__ kk_w, const float* __restrict__ kk_b,
                             const ushort* __restrict__ Bim, int layer,
                             ushort* __restrict__ kern) {
  __shared__ ushort As[128 * KKP];
  __shared__ ushort Bs[128 * KKP];
  __shared__ float bias_s[128];
  int n0 = blockIdx.x * 128;           // 4 col tiles
  int m0 = blockIdx.y * 128;           // 192 row tiles
  int tid = threadIdx.x;
  if (tid < 128) bias_s[tid] = kk_b[layer * LROWS + m0 + tid];
  const float*  Ap = kk_w + ((size_t)layer * LROWS + m0) * 192;
  const ushort* Bp = Bim + (size_t)n0 * 192;
  int w = tid >> 6, lane = tid & 63, q = lane >> 4, ln = lane & 15;
  int wm = (w >> 1) * 64, wn = (w & 1) * 64;
  f4 acc[4][4] = {};
  for (int kc = 0; kc < 2; kc++) {
    int kbase = kc * 96;
    __syncthreads();
    for (int i = tid; i < 128 * 24; i += 256) {       // A: fp32 -> bf16
      int m = i / 24, c4 = (i % 24) * 4;
      float4 v = *(const float4*)(Ap + (size_t)m * 192 + kbase + c4);
      us4 o = {f2b(v.x), f2b(v.y), f2b(v.z), f2b(v.w)};
      *(us4*)(&As[m * KKP + c4]) = o;
    }
    for (int i = tid; i < 128 * 12; i += 256) {       // B: bf16 copy
      int n = i / 12, c8 = (i % 12) * 8;
      us8 v = *(const us8*)(Bp + (size_t)n * 192 + kbase + c8);
      *(us8*)(&Bs[n * KKP + c8]) = v;
    }
    __syncthreads();
    #pragma unroll
    for (int ks = 0; ks < 3; ks++) {
      int kb = ks * 32 + q * 8;
      bh8 af[4], bf[4];
      #pragma unroll
      for (int mi = 0; mi < 4; mi++) af[mi] = *(const bh8*)(&As[(wm + mi * 16 + ln) * KKP + kb]);
      #pragma unroll
      for (int ni = 0; ni < 4; ni++) bf[ni] = *(const bh8*)(&Bs[(wn + ni * 16 + ln) * KKP + kb]);
      #pragma unroll
      for (int mi = 0; mi < 4; mi++)
        #pragma unroll
        for (int ni = 0; ni < 4; ni++) acc[mi][ni] = mfma16(af[mi], bf[ni], acc[mi][ni]);
    }
  }
  #pragma unroll
  for (int mi = 0; mi < 4; mi++) {
    int rloc = wm + mi * 16 + q * 4;
    #pragma unroll
    for (int ni = 0; ni < 4; ni++) {
      int col = n0 + wn + ni * 16 + ln;
      us4 o;
      #pragma unroll
      for (int r = 0; r < 4; r++) o[r] = f2b(acc[mi][ni][r] + bias_s[rloc + r]);
      *(us4*)(kern + (size_t)col * LROWS + m0 + rloc) = o;
    }
  }
}

// ---------------- dilated conv3 (lrelu in, lrelu out) ----------------
template <int DIL>
__launch_bounds__(256, 2)
__global__ void conv_layer(const float* __restrict__ h, const float* __restrict__ wct,
                           const float* __restrict__ conv_b, int layer, float* __restrict__ y) {
  constexpr int W = 128 + 2 * DIL;
  constexpr int WP = (W + 3) & ~3;
  __shared__ float hs[32][WP];
  __shared__ float Ws[32 * 3 * 64];
  int blk = blockIdx.x, b = blk >> 8, tt = blk & 255;
  int t0 = tt * 128;
  int tid = threadIdx.x;
  int tc = tid & 7, ts = tid >> 3;
  int c0 = tc * 8, s0 = ts * 4;
  float acc[8][4];
  #pragma unroll
  for (int r = 0; r < 8; r++) {
    float bv = conv_b[layer * 64 + c0 + r];
    #pragma unroll
    for (int j = 0; j < 4; j++) acc[r][j] = bv;
  }
  const float* hb = h + (size_t)b * 64 * OLEN;
  for (int half = 0; half < 2; half++) {
    __syncthreads();
    for (int idx = tid; idx < 32 * W; idx += 256) {
      int cil = idx / W, u = idx % W;
      int t = t0 - DIL + u;
      hs[cil][u] = (t >= 0 && t < OLEN) ? lrelu(hb[(half * 32 + cil) * OLEN + t], 0.2f) : 0.f;
    }
    const float* wp = wct + (layer * 64 + half * 32) * 192;
    for (int idx = tid; idx < 6144; idx += 256) Ws[idx] = wp[idx];
    __syncthreads();
    for (int cil = 0; cil < 32; cil++) {
      #pragma unroll
      for (int k = 0; k < 3; k++) {
        float a[8], xv[4];
        const float* wq = &Ws[(cil * 3 + k) * 64 + c0];
        #pragma unroll
        for (int u = 0; u < 8; u++) a[u] = wq[u];
        const float* xq = &hs[cil][s0 + k * DIL];
        #pragma unroll
        for (int j = 0; j < 4; j++) xv[j] = xq[j];
        #pragma unroll
        for (int r = 0; r < 8; r++)
          #pragma unroll
          for (int j = 0; j < 4; j++) acc[r][j] += a[r] * xv[j];
      }
    }
  }
  float* yb = y + (size_t)b * 64 * OLEN;
  #pragma unroll
  for (int r = 0; r < 8; r++) {
    float* yp = yb + (c0 + r) * OLEN + t0 + s0;
    #pragma unroll
    for (int j = 0; j < 4; j++) yp[j] = lrelu(acc[r][j], 0.2f);
  }
}

// ---------------- LVC + sigmoid*tanh gate, h += ----------------
__launch_bounds__(256, 2)
__global__ void lvc_gate(const float* __restrict__ y, const ushort* __restrict__ kern,
                         const float* __restrict__ bias_all, int layer, float* __restrict__ h) {
  __shared__ float ys[64][132];
  __shared__ float Ks[16 * 3 * 128];
  int blk = blockIdx.x;
  int sh = blk & 1, l = (blk >> 1) & 127, b = blk >> 8;
  int t0 = l * 256 + sh * 128;
  int tid = threadIdx.x;
  const float* yb = y + (size_t)b * 64 * OLEN;
  for (int idx = tid; idx < 64 * 130; idx += 256) {
    int ci = idx / 130, j = idx % 130;
    int t = t0 - 1 + j;
    ys[ci][j] = (t >= 0 && t < OLEN) ? yb[ci * OLEN + t] : 0.f;
  }
  int tc = tid & 15, ts = tid >> 4;
  int c0 = tc * 4, s0 = ts * 8;
  float acc[8][8];
  #pragma unroll
  for (int r = 0; r < 4; r++) {
    float blo = bias_all[(b * 512 + layer * 128 + c0 + r) * 128 + l];
    float bhi = bias_all[(b * 512 + layer * 128 + c0 + 64 + r) * 128 + l];
    #pragma unroll
    for (int j = 0; j < 8; j++) { acc[r][j] = blo; acc[r + 4][j] = bhi; }
  }
  const ushort* kb_ = kern + (size_t)(b * 128 + l) * LROWS;
  for (int chunk = 0; chunk < 4; chunk++) {
    __syncthreads();
    for (int idx = tid; idx < 6144; idx += 256) {
      int ci_loc = idx / 384, rem = idx % 384, co = rem / 3, k = rem % 3;
      Ks[(ci_loc * 3 + k) * 128 + co] = b2f(kb_[chunk * 6144 + idx]);
    }
    __syncthreads();
    for (int ci_loc = 0; ci_loc < 16; ci_loc++) {
      int ci = chunk * 16 + ci_loc;
      float xv[12];
      #pragma unroll
      for (int u = 0; u < 12; u++) xv[u] = ys[ci][s0 + u];
      #pragma unroll
      for (int k = 0; k < 3; k++) {
        float alo[4], ahi[4];
        const float* kp = &Ks[(ci_loc * 3 + k) * 128];
        #pragma unroll
        for (int u = 0; u < 4; u++) alo[u] = kp[c0 + u];
        #pragma unroll
        for (int u = 0; u < 4; u++) ahi[u] = kp[c0 + 64 + u];
        #pragma unroll
        for (int r = 0; r < 4; r++)
          #pragma unroll
          for (int j = 0; j < 8; j++) {
            acc[r][j]     += alo[r] * xv[j + k];
            acc[r + 4][j] += ahi[r] * xv[j + k];
          }
      }
    }
  }
  float* hb = h + (size_t)b * 64 * OLEN;
  #pragma unroll
  for (int r = 0; r < 4; r++) {
    float* hp = hb + (c0 + r) * OLEN + t0 + s0;
    #pragma unroll
    for (int j = 0; j < 8; j++) {
      float sg = 1.f / (1.f + expf(-acc[r][j]));
      float th = tanhf(acc[r + 4][j]);
      hp[j] += sg * th;
    }
  }
}

extern "C" void kernel_launch(void* const* d_in, const int* in_sizes, int n_in,
                              void* d_out, int out_size, void* d_ws, size_t ws_size,
                              hipStream_t stream) {
  const float* x      = (const float*)d_in[0];
  const float* c      = (const float*)d_in[1];
  const float* up_w   = (const float*)d_in[2];
  const float* up_b   = (const float*)d_in[3];
  const float* kin_w  = (const float*)d_in[4];
  const float* kin_b  = (const float*)d_in[5];
  const float* kres_w = (const float*)d_in[6];
  const float* kres_b = (const float*)d_in[7];
  const float* kk_w   = (const float*)d_in[8];
  const float* kk_b   = (const float*)d_in[9];
  const float* kb_w   = (const float*)d_in[10];
  const float* kb_b   = (const float*)d_in[11];
  const float* conv_w = (const float*)d_in[12];
  const float* conv_b = (const float*)d_in[13];
  float* h = (float*)d_out;

  float* ws = (float*)d_ws;
  float* kin_t    = ws; ws += 80 * 5 * 64;
  float* kres_t   = ws; ws += 6 * 64 * 3 * 64;
  float* wct      = ws; ws += 4 * 64 * 3 * 64;
  float* hkp      = ws; ws += 4 * 64 * 128;
  float* ra       = ws; ws += 4 * 64 * 128;
  float* rb       = ws; ws += 4 * 64 * 128;
  float* hsum     = ws; ws += 4 * 64 * 128;
  float* bias_all = ws; ws += 4 * 512 * 128;
  float* ybuf     = ws; ws += (size_t)4 * 64 * OLEN;
  ushort* kern16  = (ushort*)ws; ws += (size_t)512 * LROWS / 2;
  ushort* Bim     = (ushort*)ws; ws += 4 * 128 * 192 / 2;
  ushort* xT      = (ushort*)ws; ws += 4 * 4098 * 64 / 2 + 64;
  ushort* A3      = (ushort*)ws; ws += 512 * 192 / 2;

  prep_kernel<<<288, 256, 0, stream>>>(kin_w, kres_w, conv_w, kin_t, kres_t, wct);
  prep_up_a<<<384, 256, 0, stream>>>(up_w, A3);
  prep_xt<<<256, 256, 0, stream>>>(x, xT);
  kp_head<<<512, 64, 0, stream>>>(c, kin_t, kin_b, hkp);
  const float* rin = hkp;
  float* rout = ra;
  for (int j = 0; j < 6; j++) {
    kp_res<<<512, 64, 0, stream>>>(rin, kres_t, kres_b, j, rout);
    rin = rout;
    rout = (rout == ra) ? rb : ra;
  }
  add2<<<128, 256, 0, stream>>>(hkp, rin, hsum, 32768);
  prep_bim<<<384, 256, 0, stream>>>(hsum, Bim);
  kb_conv<<<1024, 256, 0, stream>>>(hsum, kb_w, kb_b, bias_all);
  upsample_mfma<<<dim3(128, 4, 4), 256, 0, stream>>>(xT, A3, up_b, h);

  for (int layer = 0; layer < NLAYERS; layer++) {
    kk_gemm_mfma<<<dim3(4, 192), 256, 0, stream>>>(kk_w, kk_b, Bim, layer, kern16);
    switch (layer) {
      case 0: conv_layer<1><<<1024, 256, 0, stream>>>(h, wct, conv_b, layer, ybuf); break;
      case 1: conv_layer<3><<<1024, 256, 0, stream>>>(h, wct, conv_b, layer, ybuf); break;
      case 2: conv_layer<9><<<1024, 256, 0, stream>>>(h, wct, conv_b, layer, ybuf); break;
      case 3: conv_layer<27><<<1024, 256, 0, stream>>>(h, wct, conv_b, layer, ybuf); break;
    }
    lvc_gate<<<1024, 256, 0, stream>>>(ybuf, kern16, bias_all, layer, h);
  }
}

// Round 3
// 693.485 us; speedup vs baseline: 2.4537x; 1.7314x over previous
//
#include <hip/hip_runtime.h>
#include <math.h>

#define CIN 64
#define NLAYERS 4
#define HOP 256
#define ILEN 4096
#define OLEN 32768
#define LROWS 24576   // rows of kk per layer = 64*128*3
#define YROWS 32832   // 32 pad + 32768 + 32 pad

typedef unsigned int uint;
typedef unsigned short ushort;
typedef __attribute__((ext_vector_type(8))) short bh8;
typedef __attribute__((ext_vector_type(4))) float f4;
typedef __attribute__((ext_vector_type(8))) unsigned short us8;
typedef __attribute__((ext_vector_type(4))) unsigned short us4;

__device__ __forceinline__ float lrelu(float x, float s) { return x >= 0.f ? x : s * x; }

__device__ __forceinline__ ushort f2b(float f) {       // fp32 -> bf16 (RNE)
  uint u = __float_as_uint(f);
  u = u + 0x7fff + ((u >> 16) & 1);
  return (ushort)(u >> 16);
}
__device__ __forceinline__ float b2f(ushort u) {
  return __uint_as_float(((uint)u) << 16);
}
__device__ __forceinline__ f4 mfma16(bh8 a, bh8 b, f4 c) {
  return __builtin_amdgcn_mfma_f32_16x16x32_bf16(a, b, c, 0, 0, 0);
}

// ---------------- prep: weight transposes ----------------
__global__ void prep_kernel(const float* __restrict__ kin_w, const float* __restrict__ kres_w,
                            const float* __restrict__ conv_w,
                            float* __restrict__ kin_t, float* __restrict__ kres_t,
                            ushort* __restrict__ wct_b) {
  int i = blockIdx.x * 256 + threadIdx.x;
  if (i < 80 * 5 * 64) {               // kin_t[cc][t][ch] <- kin_w[ch][cc][t]
    int ch = i & 63, r = i >> 6, t = r % 5, cc = r / 5;
    kin_t[i] = kin_w[(ch * 80 + cc) * 5 + t];
  }
  if (i < 6 * 64 * 3 * 64) {           // kres_t[j][ci][k][ch] <- kres_w[j][ch][ci][k]
    int ch = i & 63, r = i >> 6, k = r % 3; r /= 3; int ci = r & 63, j = r >> 6;
    kres_t[i] = kres_w[((j * 64 + ch) * 64 + ci) * 3 + k];
  }
  if (i < 4 * 3 * 64 * 64) {           // wct_b[l][ks][co][ci] <- bf16(conv_w[l][co][ci][ks])
    int ci = i & 63, r = i >> 6, co = r & 63; r >>= 6; int ks = r % 3, l = r / 3;
    wct_b[i] = f2b(conv_w[((l * 64 + co) * 64 + ci) * 3 + ks]);
  }
}

// zero the 32-row pads of yT (ws is poisoned 0xAA every call)
__global__ void zero_pads(ushort* __restrict__ yT) {
  int i = blockIdx.x * 256 + threadIdx.x;     // 2048 us8 groups
  if (i >= 2048) return;
  int b = i >> 9, rr = i & 511;
  int row = rr >> 3, ch = rr & 7;
  int grow = (row < 32) ? row : (32768 + row);
  us8 z = {0, 0, 0, 0, 0, 0, 0, 0};
  *(us8*)(yT + ((size_t)b * YROWS + grow) * 64 + ch * 8) = z;
}

// A matrix for upsample MFMA: A3[m=co*8+ph][k=(u+1)*64+ci], u = input shift -1/0/+1
__global__ void prep_up_a(const float* __restrict__ up_w, ushort* __restrict__ A3) {
  int i = blockIdx.x * 256 + threadIdx.x;
  if (i >= 512 * 192) return;
  int k = i % 192, m = i / 192;
  int co = m >> 3, ph = m & 7;
  int u = k / 64 - 1, ci = k % 64;
  int kk0 = (11 - ph) & 7;
  int off = (ph < 4) ? -1 : 0;
  int tap = u - off;
  float v = 0.f;
  if (tap == 0 || tap == 1) {
    int a = 15 - kk0 - 8 * tap;
    v = up_w[(ci * 64 + co) * 16 + a];
  }
  A3[i] = f2b(v);
}

// xT[b][1+s][ci] = bf16(lrelu(x[b][ci][s])), rows 0 and 4097 zero-padded
__global__ void prep_xt(const float* __restrict__ x, ushort* __restrict__ xT) {
  __shared__ float ls[64][65];
  int blk = blockIdx.x, b = blk >> 6, st = blk & 63;
  int s0 = st * 64;
  int tid = threadIdx.x;
  int c2 = tid >> 6, s = tid & 63;
  #pragma unroll
  for (int r = 0; r < 16; r++) {
    int ci = r * 4 + c2;
    ls[ci][s] = lrelu(x[((size_t)b * 64 + ci) * ILEN + s0 + s], 0.2f);
  }
  __syncthreads();
  int ci = tid & 63, r2 = tid >> 6;
  #pragma unroll
  for (int r = 0; r < 16; r++) {
    int ss = r * 4 + r2;
    xT[((size_t)b * 4098 + 1 + s0 + ss) * 64 + ci] = f2b(ls[ci][ss]);
  }
  if (st == 0) {
    if (tid < 64) xT[((size_t)b * 4098) * 64 + tid] = 0;
    else if (tid < 128) xT[((size_t)b * 4098 + 4097) * 64 + (tid - 64)] = 0;
  }
}

// B matrix for kk GEMM (layer-invariant): Bim[col=b*128+l][k=hid*3+t] = hsum[b][hid][l+t-1]
__global__ void prep_bim(const float* __restrict__ hsum, ushort* __restrict__ Bim) {
  int i = blockIdx.x * 256 + threadIdx.x;
  if (i >= 4 * 128 * 192) return;
  int k = i % 192, l = (i / 192) & 127, b = i / (192 * 128);
  int hid = k / 3, t = k % 3, li = l + t - 1;
  float v = (li >= 0 && li < 128) ? hsum[(b * 64 + hid) * 128 + li] : 0.f;
  Bim[i] = f2b(v);
}

// ---------------- kernel predictor head: conv5 (80->64) + lrelu(0.1) ----------------
__global__ void kp_head(const float* __restrict__ c, const float* __restrict__ kin_t,
                        const float* __restrict__ kin_b, float* __restrict__ hkp) {
  int blk = blockIdx.x, b = blk >> 7, l = blk & 127;
  int ch = threadIdx.x;
  float acc = kin_b[ch];
  for (int cc = 0; cc < 80; cc++) {
    const float* cp = c + (b * 80 + cc) * 128;
    #pragma unroll
    for (int t = 0; t < 5; t++) {
      int li = l + t - 2;
      if (li >= 0 && li < 128) acc += cp[li] * kin_t[(cc * 5 + t) * 64 + ch];
    }
  }
  hkp[(b * 64 + ch) * 128 + l] = lrelu(acc, 0.1f);
}

// ---------------- residual conv3 (64->64) + lrelu(0.1) ----------------
__global__ void kp_res(const float* __restrict__ rin, const float* __restrict__ kres_t,
                       const float* __restrict__ kres_b, int j, float* __restrict__ rout) {
  __shared__ float rs[192];
  int blk = blockIdx.x, b = blk >> 7, l = blk & 127;
  int ch = threadIdx.x;
  for (int idx = ch; idx < 192; idx += 64) {
    int ci = idx / 3, k = idx % 3, li = l + k - 1;
    rs[idx] = (li >= 0 && li < 128) ? rin[(b * 64 + ci) * 128 + li] : 0.f;
  }
  __syncthreads();
  float acc = kres_b[j * 64 + ch];
  const float* wt = kres_t + j * 12288 + ch;
  for (int idx = 0; idx < 192; idx++) acc += rs[idx] * wt[idx * 64];
  rout[(b * 64 + ch) * 128 + l] = lrelu(acc, 0.1f);
}

__global__ void add2(const float* __restrict__ a, const float* __restrict__ b,
                     float* __restrict__ o, int n) {
  int i = blockIdx.x * 256 + threadIdx.x;
  if (i < n) o[i] = a[i] + b[i];
}

// ---------------- bias predictor conv3 (64->512) ----------------
__global__ void kb_conv(const float* __restrict__ hsum, const float* __restrict__ kb_w,
                        const float* __restrict__ kb_b, float* __restrict__ bias_all) {
  int i = blockIdx.x * 256 + threadIdx.x;   // over 4*512*128
  int l = i & 127, r = (i >> 7) & 511, b = i >> 16;
  float acc = kb_b[r];
  const float* wp = kb_w + r * 192;
  const float* hp = hsum + b * 64 * 128;
  for (int hid = 0; hid < 64; hid++) {
    #pragma unroll
    for (int t = 0; t < 3; t++) {
      int li = l + t - 1;
      if (li >= 0 && li < 128) acc += hp[hid * 128 + li] * wp[hid * 3 + t];
    }
  }
  bias_all[i] = acc;
}

// ---------------- upsample as MFMA GEMM: M=512 (co*8+ph), N=4096 (s), K=192 ----------------
#define UP_KP 200
__launch_bounds__(256, 2)
__global__ void upsample_mfma(const ushort* __restrict__ xT, const ushort* __restrict__ A3,
                              const float* __restrict__ up_b, float* __restrict__ h) {
  __shared__ ushort As[128 * UP_KP];   // 50 KB
  __shared__ ushort Bs[32 * UP_KP];    // 12.5 KB
  int s0 = blockIdx.x * 32;            // 128 s-tiles
  int m0 = blockIdx.y * 128;           // 4 co-tiles (16 co each)
  int b  = blockIdx.z;
  int tid = threadIdx.x;
  {
    const ushort* src = A3 + (size_t)m0 * 192;
    for (int i = tid; i < 128 * 24; i += 256) {
      int m = i / 24, c8 = (i % 24) * 8;
      us8 v = *(const us8*)(src + (size_t)m * 192 + c8);
      *(us8*)(&As[m * UP_KP + c8]) = v;
    }
  }
  for (int i = tid; i < 32 * 24; i += 256) {
    int n = i / 24, rr = i % 24, u = rr / 8, c8 = (rr % 8) * 8;
    us8 v = *(const us8*)(xT + ((size_t)b * 4098 + s0 + n + u) * 64 + c8);
    *(us8*)(&Bs[n * UP_KP + u * 64 + c8]) = v;
  }
  __syncthreads();
  int w = tid >> 6, lane = tid & 63, q = lane >> 4, ln = lane & 15;
  int wm = w * 32;
  f4 acc[2][2] = {};
  #pragma unroll
  for (int ks = 0; ks < 6; ks++) {
    int kb = ks * 32 + q * 8;
    bh8 a0 = *(const bh8*)(&As[(wm + ln) * UP_KP + kb]);
    bh8 a1 = *(const bh8*)(&As[(wm + 16 + ln) * UP_KP + kb]);
    bh8 b0 = *(const bh8*)(&Bs[ln * UP_KP + kb]);
    bh8 b1 = *(const bh8*)(&Bs[(16 + ln) * UP_KP + kb]);
    acc[0][0] = mfma16(a0, b0, acc[0][0]);
    acc[0][1] = mfma16(a0, b1, acc[0][1]);
    acc[1][0] = mfma16(a1, b0, acc[1][0]);
    acc[1][1] = mfma16(a1, b1, acc[1][1]);
  }
  #pragma unroll
  for (int mi = 0; mi < 2; mi++) {
    int mloc = wm + mi * 16 + q * 4;
    int co = (m0 + mloc) >> 3;
    int ph0 = mloc & 7;
    float bias = up_b[co];
    #pragma unroll
    for (int ni = 0; ni < 2; ni++) {
      int n = s0 + ni * 16 + ln;
      f4 v = acc[mi][ni];
      float4 o = make_float4(v[0] + bias, v[1] + bias, v[2] + bias, v[3] + bias);
      *(float4*)(h + ((size_t)b * 64 + co) * OLEN + n * 8 + ph0) = o;
    }
  }
}

// ---------------- kk GEMM (MFMA), permuted rows m = ks*8192 + co*64 + ci ----------------
#define KKP 104
__launch_bounds__(256, 2)
__global__ void kk_gemm_mfma(const float* __restrict__ kk_w, const float* __restrict__ kk_b,
                             const ushort* __restrict__ Bim, int layer,
                             ushort* __restrict__ kern) {
  __shared__ ushort As[128 * KKP];
  __shared__ ushort Bs[128 * KKP];
  __shared__ float bias_s[128];
  int n0 = blockIdx.x * 128;           // 4 col tiles
  int m0 = blockIdx.y * 128;           // 192 row tiles (new-index m)
  int tid = threadIdx.x;
  if (tid < 128) {
    int m = m0 + tid;
    int ks = m >> 13, co = (m & 8191) >> 6, ci = m & 63;
    bias_s[tid] = kk_b[layer * LROWS + ci * 384 + co * 3 + ks];
  }
  const ushort* Bp = Bim + (size_t)n0 * 192;
  int w = tid >> 6, lane = tid & 63, q = lane >> 4, ln = lane & 15;
  int wm = (w >> 1) * 64, wn = (w & 1) * 64;
  f4 acc[4][4] = {};
  for (int kc = 0; kc < 2; kc++) {
    int kbase = kc * 96;
    __syncthreads();
    for (int i = tid; i < 128 * 24; i += 256) {       // A: fp32 -> bf16, permuted rows
      int ml = i / 24, c4 = (i % 24) * 4;
      int m = m0 + ml;
      int ks = m >> 13, co = (m & 8191) >> 6, ci = m & 63;
      int r = ci * 384 + co * 3 + ks;
      float4 v = *(const float4*)(kk_w + ((size_t)layer * LROWS + r) * 192 + kbase + c4);
      us4 o = {f2b(v.x), f2b(v.y), f2b(v.z), f2b(v.w)};
      *(us4*)(&As[ml * KKP + c4]) = o;
    }
    for (int i = tid; i < 128 * 12; i += 256) {       // B: bf16 copy
      int n = i / 12, c8 = (i % 12) * 8;
      us8 v = *(const us8*)(Bp + (size_t)n * 192 + kbase + c8);
      *(us8*)(&Bs[n * KKP + c8]) = v;
    }
    __syncthreads();
    #pragma unroll
    for (int ks = 0; ks < 3; ks++) {
      int kb = ks * 32 + q * 8;
      bh8 af[4], bf[4];
      #pragma unroll
      for (int mi = 0; mi < 4; mi++) af[mi] = *(const bh8*)(&As[(wm + mi * 16 + ln) * KKP + kb]);
      #pragma unroll
      for (int ni = 0; ni < 4; ni++) bf[ni] = *(const bh8*)(&Bs[(wn + ni * 16 + ln) * KKP + kb]);
      #pragma unroll
      for (int mi = 0; mi < 4; mi++)
        #pragma unroll
        for (int ni = 0; ni < 4; ni++) acc[mi][ni] = mfma16(af[mi], bf[ni], acc[mi][ni]);
    }
  }
  // bounce epilogue: coalesced kern stores. Cb[col][m64] (swizzled), 16 KB in As space.
  ushort* Cb = As;
  int myhalf = wm >> 6;
  __syncthreads();
  for (int half = 0; half < 2; half++) {
    if (myhalf == half) {
      #pragma unroll
      for (int mi = 0; mi < 4; mi++) {
        int rloc = wm + mi * 16 + q * 4;
        #pragma unroll
        for (int ni = 0; ni < 4; ni++) {
          int col = wn + ni * 16 + ln;
          #pragma unroll
          for (int r = 0; r < 4; r++) {
            int m64 = (rloc + r) & 63;
            ushort v = f2b(acc[mi][ni][r] + bias_s[rloc + r]);
            Cb[col * 64 + (((m64 >> 3) ^ (col & 7)) * 8) + (m64 & 7)] = v;
          }
        }
      }
    }
    __syncthreads();
    for (int g = tid; g < 1024; g += 256) {
      int col = g >> 3, mc = g & 7;
      us8 v = *(const us8*)(&Cb[col * 64 + ((mc ^ (col & 7)) * 8)]);
      *(us8*)(kern + (size_t)(n0 + col) * LROWS + m0 + half * 64 + mc * 8) = v;
    }
    __syncthreads();
  }
}

// ---------------- dilated conv3 via MFMA (lrelu in, lrelu out) -> yT bf16 ----------------
template <int DIL>
__launch_bounds__(256, 2)
__global__ void conv_mfma(const float* __restrict__ h, const ushort* __restrict__ wct_b,
                          const float* __restrict__ conv_b, int layer, ushort* __restrict__ yT) {
  __shared__ float hs[64][193];        // fp32 window t0-32 .. t0+160, lrelu applied
  __shared__ ushort Bs[192 * 64];      // bf16 transposed [j][ci], xor-chunk swizzled
  int t0 = (blockIdx.x) * 128;
  int b = blockIdx.y;
  int tid = threadIdx.x;
  const float* hb = h + (size_t)b * 64 * OLEN;
  // stage 1: coalesced fp32 load (aligned float4)
  for (int g = tid; g < 64 * 48; g += 256) {
    int ci = g / 48, j4 = (g % 48) * 4;
    int t = t0 - 32 + j4;
    float4 v = make_float4(0.f, 0.f, 0.f, 0.f);
    if (t >= 0 && t < OLEN) v = *(const float4*)(hb + (size_t)ci * OLEN + t);
    hs[ci][j4 + 0] = lrelu(v.x, 0.2f);
    hs[ci][j4 + 1] = lrelu(v.y, 0.2f);
    hs[ci][j4 + 2] = lrelu(v.z, 0.2f);
    hs[ci][j4 + 3] = lrelu(v.w, 0.2f);
  }
  __syncthreads();
  // stage 2: transpose to Bs[j][ci] bf16
  for (int g = tid; g < 192 * 8; g += 256) {
    int j = g >> 3, ch = g & 7;
    us8 o;
    #pragma unroll
    for (int u = 0; u < 8; u++) o[u] = f2b(hs[ch * 8 + u][j]);
    *(us8*)(&Bs[(j * 8 + (ch ^ (j & 7))) * 8]) = o;
  }
  __syncthreads();
  int w = tid >> 6, lane = tid & 63, q = lane >> 4, ln = lane & 15;
  int n0w = w * 32;
  f4 acc[4][2] = {};
  #pragma unroll
  for (int ks = 0; ks < 3; ks++) {
    #pragma unroll
    for (int kst = 0; kst < 2; kst++) {
      bh8 bfr[2];
      #pragma unroll
      for (int nt = 0; nt < 2; nt++) {
        int j = 32 + n0w + nt * 16 + ln + (ks - 1) * DIL;
        bfr[nt] = *(const bh8*)(&Bs[(j * 8 + ((kst * 4 + q) ^ (j & 7))) * 8]);
      }
      #pragma unroll
      for (int mt = 0; mt < 4; mt++) {
        bh8 a = *(const bh8*)(wct_b + (((layer * 3 + ks) * 64) + mt * 16 + ln) * 64 + kst * 32 + q * 8);
        #pragma unroll
        for (int nt = 0; nt < 2; nt++) acc[mt][nt] = mfma16(a, bfr[nt], acc[mt][nt]);
      }
    }
  }
  // epilogue: lrelu(acc+bias) -> bf16 -> bounce -> coalesced yT store
  ushort* yb = (ushort*)hs;            // 16 KB alias (hs dead now)
  #pragma unroll
  for (int mt = 0; mt < 4; mt++) {
    #pragma unroll
    for (int r = 0; r < 4; r++) {
      int co = mt * 16 + q * 4 + r;
      float cb = conv_b[layer * 64 + co];
      #pragma unroll
      for (int nt = 0; nt < 2; nt++) {
        int tl = n0w + nt * 16 + ln;
        ushort v = f2b(lrelu(acc[mt][nt][r] + cb, 0.2f));
        yb[(tl * 8 + ((co >> 3) ^ (tl & 7))) * 8 + (co & 7)] = v;
      }
    }
  }
  __syncthreads();
  for (int g = tid; g < 1024; g += 256) {
    int tl = g >> 3, ch = g & 7;
    us8 v = *(const us8*)(&yb[(tl * 8 + (ch ^ (tl & 7))) * 8]);
    *(us8*)(yT + ((size_t)b * YROWS + 32 + t0 + tl) * 64 + ch * 8) = v;
  }
}

// ---------------- LVC (MFMA) + sigmoid*tanh gate, h += ----------------
__launch_bounds__(256, 2)
__global__ void lvc_gate_mfma(const ushort* __restrict__ yT, const ushort* __restrict__ kern,
                              const float* __restrict__ bias_all, int layer,
                              float* __restrict__ h) {
  __shared__ ushort As[LROWS];         // 48 KB: kern slice [ks][co][ci], xor-chunk swizzled
  __shared__ ushort Ys[1040 * 8];      // 16.6 KB: yT rows t0-1 .. t0+128, swizzled
  int sh = blockIdx.x, l = blockIdx.y, b = blockIdx.z;
  int t0 = l * 256 + sh * 128;
  int col = b * 128 + l;
  int tid = threadIdx.x;
  // stage A: coalesced kern read, swizzled LDS write
  {
    const ushort* kp = kern + (size_t)col * LROWS;
    for (int g = tid; g < 3072; g += 256) {
      us8 v = *(const us8*)(kp + g * 8);
      int co = (g & 1023) >> 3, ch = g & 7;
      *(us8*)(&As[((g & ~7) | (ch ^ (co & 7))) * 8]) = v;
    }
  }
  // stage B: yT window
  {
    const ushort* yp = yT + ((size_t)b * YROWS + 32 + t0 - 1) * 64;
    for (int g = tid; g < 1040; g += 256) {
      us8 v = *(const us8*)(yp + g * 8);
      int j = g >> 3, ch = g & 7;
      *(us8*)(&Ys[(j * 8 + (ch ^ (j & 7))) * 8]) = v;
    }
  }
  __syncthreads();
  int w = tid >> 6, lane = tid & 63, q = lane >> 4, ln = lane & 15;
  int n0w = w * 32;
  f4 acc[8][2] = {};
  #pragma unroll
  for (int ks = 0; ks < 3; ks++) {
    #pragma unroll
    for (int kst = 0; kst < 2; kst++) {
      bh8 bfr[2];
      #pragma unroll
      for (int nt = 0; nt < 2; nt++) {
        int j = n0w + nt * 16 + ln + ks;
        bfr[nt] = *(const bh8*)(&Ys[(j * 8 + ((kst * 4 + q) ^ (j & 7))) * 8]);
      }
      #pragma unroll
      for (int mt = 0; mt < 8; mt++) {
        int co = mt * 16 + ln;
        bh8 a = *(const bh8*)(&As[(ks * 1024 + co * 8 + ((kst * 4 + q) ^ (co & 7))) * 8]);
        #pragma unroll
        for (int nt = 0; nt < 2; nt++) acc[mt][nt] = mfma16(a, bfr[nt], acc[mt][nt]);
      }
    }
  }
  // epilogue: gate + h accumulate (coalesced per 16-lane row)
  float* hb = h + (size_t)b * 64 * OLEN;
  const float* bp = bias_all + (size_t)(b * 512 + layer * 128) * 128 + l;
  #pragma unroll
  for (int mt = 0; mt < 4; mt++) {
    #pragma unroll
    for (int nt = 0; nt < 2; nt++) {
      int t = t0 + n0w + nt * 16 + ln;
      #pragma unroll
      for (int r = 0; r < 4; r++) {
        int co = mt * 16 + q * 4 + r;
        float lo = acc[mt][nt][r] + bp[(size_t)co * 128];
        float hi = acc[mt + 4][nt][r] + bp[(size_t)(co + 64) * 128];
        float sg = 1.f / (1.f + expf(-lo));
        float th = tanhf(hi);
        float* hp = hb + (size_t)co * OLEN + t;
        *hp += sg * th;
      }
    }
  }
}

extern "C" void kernel_launch(void* const* d_in, const int* in_sizes, int n_in,
                              void* d_out, int out_size, void* d_ws, size_t ws_size,
                              hipStream_t stream) {
  const float* x      = (const float*)d_in[0];
  const float* c      = (const float*)d_in[1];
  const float* up_w   = (const float*)d_in[2];
  const float* up_b   = (const float*)d_in[3];
  const float* kin_w  = (const float*)d_in[4];
  const float* kin_b  = (const float*)d_in[5];
  const float* kres_w = (const float*)d_in[6];
  const float* kres_b = (const float*)d_in[7];
  const float* kk_w   = (const float*)d_in[8];
  const float* kk_b   = (const float*)d_in[9];
  const float* kb_w   = (const float*)d_in[10];
  const float* kb_b   = (const float*)d_in[11];
  const float* conv_w = (const float*)d_in[12];
  const float* conv_b = (const float*)d_in[13];
  float* h = (float*)d_out;

  float* ws = (float*)d_ws;
  float* kin_t    = ws; ws += 80 * 5 * 64;
  float* kres_t   = ws; ws += 6 * 64 * 3 * 64;
  float* hkp      = ws; ws += 4 * 64 * 128;
  float* ra       = ws; ws += 4 * 64 * 128;
  float* rb       = ws; ws += 4 * 64 * 128;
  float* hsum     = ws; ws += 4 * 64 * 128;
  float* bias_all = ws; ws += 4 * 512 * 128;
  ushort* kern16  = (ushort*)ws; ws += (size_t)512 * LROWS / 2;
  ushort* Bim     = (ushort*)ws; ws += 4 * 128 * 192 / 2;
  ushort* xT      = (ushort*)ws; ws += 4 * 4098 * 64 / 2 + 64;
  ushort* A3      = (ushort*)ws; ws += 512 * 192 / 2;
  ushort* wct_b   = (ushort*)ws; ws += 4 * 3 * 64 * 64 / 2;
  ushort* yT      = (ushort*)ws; ws += (size_t)4 * YROWS * 64 / 2 + 64;

  prep_kernel<<<288, 256, 0, stream>>>(kin_w, kres_w, conv_w, kin_t, kres_t, wct_b);
  prep_up_a<<<384, 256, 0, stream>>>(up_w, A3);
  prep_xt<<<256, 256, 0, stream>>>(x, xT);
  zero_pads<<<8, 256, 0, stream>>>(yT);
  kp_head<<<512, 64, 0, stream>>>(c, kin_t, kin_b, hkp);
  const float* rin = hkp;
  float* rout = ra;
  for (int j = 0; j < 6; j++) {
    kp_res<<<512, 64, 0, stream>>>(rin, kres_t, kres_b, j, rout);
    rin = rout;
    rout = (rout == ra) ? rb : ra;
  }
  add2<<<128, 256, 0, stream>>>(hkp, rin, hsum, 32768);
  prep_bim<<<384, 256, 0, stream>>>(hsum, Bim);
  kb_conv<<<1024, 256, 0, stream>>>(hsum, kb_w, kb_b, bias_all);
  upsample_mfma<<<dim3(128, 4, 4), 256, 0, stream>>>(xT, A3, up_b, h);

  for (int layer = 0; layer < NLAYERS; layer++) {
    kk_gemm_mfma<<<dim3(4, 192), 256, 0, stream>>>(kk_w, kk_b, Bim, layer, kern16);
    switch (layer) {
      case 0: conv_mfma<1><<<dim3(256, 4), 256, 0, stream>>>(h, wct_b, conv_b, layer, yT); break;
      case 1: conv_mfma<3><<<dim3(256, 4), 256, 0, stream>>>(h, wct_b, conv_b, layer, yT); break;
      case 2: conv_mfma<9><<<dim3(256, 4), 256, 0, stream>>>(h, wct_b, conv_b, layer, yT); break;
      case 3: conv_mfma<27><<<dim3(256, 4), 256, 0, stream>>>(h, wct_b, conv_b, layer, yT); break;
    }
    lvc_gate_mfma<<<dim3(2, 128, 4), 256, 0, stream>>>(yT, kern16, bias_all, layer, h);
  }
}

// Round 5
// 635.854 us; speedup vs baseline: 2.6761x; 1.0906x over previous
//
#include <hip/hip_runtime.h>
#include <math.h>

#define CIN 64
#define NLAYERS 4
#define HOP 256
#define ILEN 4096
#define OLEN 32768
#define LROWS 24576   // rows of kk per layer = 64*128*3
#define YROWS 32832   // 32 pad + 32768 + 32 pad

typedef unsigned int uint;
typedef unsigned short ushort;
typedef __attribute__((ext_vector_type(8))) short bh8;
typedef __attribute__((ext_vector_type(4))) float f4;
typedef __attribute__((ext_vector_type(8))) unsigned short us8;
typedef __attribute__((ext_vector_type(4))) unsigned short us4;

__device__ __forceinline__ float lrelu(float x, float s) { return x >= 0.f ? x : s * x; }

__device__ __forceinline__ ushort f2b(float f) {       // fp32 -> bf16 (RNE)
  uint u = __float_as_uint(f);
  u = u + 0x7fff + ((u >> 16) & 1);
  return (ushort)(u >> 16);
}
__device__ __forceinline__ float b2f(ushort u) {
  return __uint_as_float(((uint)u) << 16);
}
__device__ __forceinline__ f4 mfma16(bh8 a, bh8 b, f4 c) {
  return __builtin_amdgcn_mfma_f32_16x16x32_bf16(a, b, c, 0, 0, 0);
}

// ---------------- prep: weight transposes ----------------
__global__ void prep_kernel(const float* __restrict__ kin_w, const float* __restrict__ kres_w,
                            const float* __restrict__ conv_w,
                            float* __restrict__ kin_t, float* __restrict__ kres_t,
                            ushort* __restrict__ wct_b) {
  int i = blockIdx.x * 256 + threadIdx.x;
  if (i < 80 * 5 * 64) {               // kin_t[cc][t][ch] <- kin_w[ch][cc][t]
    int ch = i & 63, r = i >> 6, t = r % 5, cc = r / 5;
    kin_t[i] = kin_w[(ch * 80 + cc) * 5 + t];
  }
  if (i < 6 * 64 * 3 * 64) {           // kres_t[j][ci][k][ch] <- kres_w[j][ch][ci][k]
    int ch = i & 63, r = i >> 6, k = r % 3; r /= 3; int ci = r & 63, j = r >> 6;
    kres_t[i] = kres_w[((j * 64 + ch) * 64 + ci) * 3 + k];
  }
  if (i < 4 * 3 * 64 * 64) {           // wct_b[l][ks][co][ci] <- bf16(conv_w[l][co][ci][ks])
    int ci = i & 63, r = i >> 6, co = r & 63; r >>= 6; int ks = r % 3, l = r / 3;
    wct_b[i] = f2b(conv_w[((l * 64 + co) * 64 + ci) * 3 + ks]);
  }
}

// zero the 32-row pads of yT (ws is poisoned 0xAA every call)
__global__ void zero_pads(ushort* __restrict__ yT) {
  int i = blockIdx.x * 256 + threadIdx.x;     // 2048 us8 groups
  if (i >= 2048) return;
  int b = i >> 9, rr = i & 511;
  int row = rr >> 3, ch = rr & 7;
  int grow = (row < 32) ? row : (32768 + row);
  us8 z = {0, 0, 0, 0, 0, 0, 0, 0};
  *(us8*)(yT + ((size_t)b * YROWS + grow) * 64 + ch * 8) = z;
}

// A matrix for upsample MFMA: A3[m=co*8+ph][k=(u+1)*64+ci], u = input shift -1/0/+1
__global__ void prep_up_a(const float* __restrict__ up_w, ushort* __restrict__ A3) {
  int i = blockIdx.x * 256 + threadIdx.x;
  if (i >= 512 * 192) return;
  int k = i % 192, m = i / 192;
  int co = m >> 3, ph = m & 7;
  int u = k / 64 - 1, ci = k % 64;
  int kk0 = (11 - ph) & 7;
  int off = (ph < 4) ? -1 : 0;
  int tap = u - off;
  float v = 0.f;
  if (tap == 0 || tap == 1) {
    int a = 15 - kk0 - 8 * tap;
    v = up_w[(ci * 64 + co) * 16 + a];
  }
  A3[i] = f2b(v);
}

// xT[b][1+s][ci] = bf16(lrelu(x[b][ci][s])), rows 0 and 4097 zero-padded
__global__ void prep_xt(const float* __restrict__ x, ushort* __restrict__ xT) {
  __shared__ float ls[64][65];
  int blk = blockIdx.x, b = blk >> 6, st = blk & 63;
  int s0 = st * 64;
  int tid = threadIdx.x;
  int c2 = tid >> 6, s = tid & 63;
  #pragma unroll
  for (int r = 0; r < 16; r++) {
    int ci = r * 4 + c2;
    ls[ci][s] = lrelu(x[((size_t)b * 64 + ci) * ILEN + s0 + s], 0.2f);
  }
  __syncthreads();
  int ci = tid & 63, r2 = tid >> 6;
  #pragma unroll
  for (int r = 0; r < 16; r++) {
    int ss = r * 4 + r2;
    xT[((size_t)b * 4098 + 1 + s0 + ss) * 64 + ci] = f2b(ls[ci][ss]);
  }
  if (st == 0) {
    if (tid < 64) xT[((size_t)b * 4098) * 64 + tid] = 0;
    else if (tid < 128) xT[((size_t)b * 4098 + 4097) * 64 + (tid - 64)] = 0;
  }
}

// ---------------- fused kernel predictor: head conv5 + 6x res conv3 + skip + Bim im2col ----
// grid (16 chunks, 4 batch). chunk = 8 output positions, window 24 = [l0-8, l0+16),
// c window 28 = [l0-10, l0+18). Res edge corruption cascades to [0,6)+[18,24);
// consumed region [7,17) stays exact.
__launch_bounds__(256)
__global__ void kp_fused(const float* __restrict__ c, const float* __restrict__ kin_t,
                         const float* __restrict__ kin_b, const float* __restrict__ kres_t,
                         const float* __restrict__ kres_b,
                         float* __restrict__ hsum, ushort* __restrict__ Bim) {
  __shared__ float cs[80 * 28];
  __shared__ float h0[64 * 25];
  __shared__ float bA[64 * 25];
  __shared__ float bB[64 * 25];
  int chunk = blockIdx.x, b = blockIdx.y;
  int l0 = chunk * 8;
  int tid = threadIdx.x;
  // stage c window (zero-padded)
  for (int g = tid; g < 80 * 28; g += 256) {
    int cc = g / 28, o = g % 28, gl = l0 - 10 + o;
    cs[g] = (gl >= 0 && gl < 128) ? c[(b * 80 + cc) * 128 + gl] : 0.f;
  }
  __syncthreads();
  int ch = tid & 63, grp = tid >> 6, g6 = grp * 6;
  float headr[6], acc[6];
  // head: conv5 80->64, lrelu 0.1
  {
    float bv = kin_b[ch];
    #pragma unroll
    for (int p = 0; p < 6; p++) acc[p] = bv;
    for (int cc = 0; cc < 80; cc++) {
      float cv[10];
      #pragma unroll
      for (int u = 0; u < 10; u++) cv[u] = cs[cc * 28 + g6 + u];
      #pragma unroll
      for (int t = 0; t < 5; t++) {
        float wv = kin_t[(cc * 5 + t) * 64 + ch];
        #pragma unroll
        for (int p = 0; p < 6; p++) acc[p] += cv[p + t] * wv;
      }
    }
    #pragma unroll
    for (int p = 0; p < 6; p++) {
      int gl = l0 - 8 + g6 + p;
      float v = (gl >= 0 && gl < 128) ? lrelu(acc[p], 0.1f) : 0.f;
      headr[p] = v;
      h0[ch * 25 + g6 + p] = v;
    }
  }
  __syncthreads();
  // 6 residual conv3 layers, ping-pong (no LDS pointer array: addrspace cast issue)
  const float* rin = h0;
  for (int j = 0; j < 6; j++) {
    float* rout = ((j & 1) == 0) ? bA : bB;
    float bv = kres_b[j * 64 + ch];
    #pragma unroll
    for (int p = 0; p < 6; p++) acc[p] = bv;
    const float* wbase = kres_t + j * 12288 + ch;
    for (int ci = 0; ci < 64; ci++) {
      float rv[8];
      #pragma unroll
      for (int u = 0; u < 8; u++) {
        int idx = g6 - 1 + u;
        idx = idx < 0 ? 0 : (idx > 23 ? 23 : idx);
        rv[u] = rin[ci * 25 + idx];
      }
      #pragma unroll
      for (int k = 0; k < 3; k++) {
        float wv = wbase[(ci * 3 + k) * 64];
        #pragma unroll
        for (int p = 0; p < 6; p++) acc[p] += rv[p + k] * wv;
      }
    }
    #pragma unroll
    for (int p = 0; p < 6; p++) {
      int gl = l0 - 8 + g6 + p;
      rout[ch * 25 + g6 + p] = (gl >= 0 && gl < 128) ? lrelu(acc[p], 0.1f) : 0.f;
    }
    __syncthreads();
    rin = rout;
  }
  // final: hsum = head + res6 (h0 reusable as hfin), then Bim im2col
  #pragma unroll
  for (int p = 0; p < 6; p++) {
    int pw = g6 + p;
    int gl = l0 - 8 + pw;
    float hs = (gl >= 0 && gl < 128) ? headr[p] + bB[ch * 25 + pw] : 0.f;
    h0[ch * 25 + pw] = hs;
    if (pw >= 8 && pw < 16) hsum[(b * 64 + ch) * 128 + gl] = hs;
  }
  __syncthreads();
  for (int g = tid; g < 512; g += 256) {
    int chh = g & 63, cl = g >> 6;
    int col = l0 + cl, pw = 8 + cl;
    ushort* bp = Bim + ((size_t)(b * 128 + col)) * 192 + chh * 3;
    bp[0] = f2b(h0[chh * 25 + pw - 1]);
    bp[1] = f2b(h0[chh * 25 + pw]);
    bp[2] = f2b(h0[chh * 25 + pw + 1]);
  }
}

// ---------------- bias predictor conv3 (64->512) ----------------
__global__ void kb_conv(const float* __restrict__ hsum, const float* __restrict__ kb_w,
                        const float* __restrict__ kb_b, float* __restrict__ bias_all) {
  int i = blockIdx.x * 256 + threadIdx.x;   // over 4*512*128
  int l = i & 127, r = (i >> 7) & 511, b = i >> 16;
  float acc = kb_b[r];
  const float* wp = kb_w + r * 192;
  const float* hp = hsum + b * 64 * 128;
  for (int hid = 0; hid < 64; hid++) {
    #pragma unroll
    for (int t = 0; t < 3; t++) {
      int li = l + t - 1;
      if (li >= 0 && li < 128) acc += hp[hid * 128 + li] * wp[hid * 3 + t];
    }
  }
  bias_all[i] = acc;
}

// ---------------- upsample as MFMA GEMM: M=512 (co*8+ph), N=4096 (s), K=192 ----------------
#define UP_KP 200
__launch_bounds__(256, 2)
__global__ void upsample_mfma(const ushort* __restrict__ xT, const ushort* __restrict__ A3,
                              const float* __restrict__ up_b, float* __restrict__ h) {
  __shared__ ushort As[128 * UP_KP];   // 50 KB
  __shared__ ushort Bs[32 * UP_KP];    // 12.5 KB
  int s0 = blockIdx.x * 32;            // 128 s-tiles
  int m0 = blockIdx.y * 128;           // 4 co-tiles (16 co each)
  int b  = blockIdx.z;
  int tid = threadIdx.x;
  {
    const ushort* src = A3 + (size_t)m0 * 192;
    for (int i = tid; i < 128 * 24; i += 256) {
      int m = i / 24, c8 = (i % 24) * 8;
      us8 v = *(const us8*)(src + (size_t)m * 192 + c8);
      *(us8*)(&As[m * UP_KP + c8]) = v;
    }
  }
  for (int i = tid; i < 32 * 24; i += 256) {
    int n = i / 24, rr = i % 24, u = rr / 8, c8 = (rr % 8) * 8;
    us8 v = *(const us8*)(xT + ((size_t)b * 4098 + s0 + n + u) * 64 + c8);
    *(us8*)(&Bs[n * UP_KP + u * 64 + c8]) = v;
  }
  __syncthreads();
  int w = tid >> 6, lane = tid & 63, q = lane >> 4, ln = lane & 15;
  int wm = w * 32;
  f4 acc[2][2] = {};
  #pragma unroll
  for (int ks = 0; ks < 6; ks++) {
    int kb = ks * 32 + q * 8;
    bh8 a0 = *(const bh8*)(&As[(wm + ln) * UP_KP + kb]);
    bh8 a1 = *(const bh8*)(&As[(wm + 16 + ln) * UP_KP + kb]);
    bh8 b0 = *(const bh8*)(&Bs[ln * UP_KP + kb]);
    bh8 b1 = *(const bh8*)(&Bs[(16 + ln) * UP_KP + kb]);
    acc[0][0] = mfma16(a0, b0, acc[0][0]);
    acc[0][1] = mfma16(a0, b1, acc[0][1]);
    acc[1][0] = mfma16(a1, b0, acc[1][0]);
    acc[1][1] = mfma16(a1, b1, acc[1][1]);
  }
  #pragma unroll
  for (int mi = 0; mi < 2; mi++) {
    int mloc = wm + mi * 16 + q * 4;
    int co = (m0 + mloc) >> 3;
    int ph0 = mloc & 7;
    float bias = up_b[co];
    #pragma unroll
    for (int ni = 0; ni < 2; ni++) {
      int n = s0 + ni * 16 + ln;
      f4 v = acc[mi][ni];
      float4 o = make_float4(v[0] + bias, v[1] + bias, v[2] + bias, v[3] + bias);
      *(float4*)(h + ((size_t)b * 64 + co) * OLEN + n * 8 + ph0) = o;
    }
  }
}

// ---------------- kk GEMM (MFMA), permuted rows m = ks*8192 + co*64 + ci ----------------
#define KKP 104
__launch_bounds__(256, 2)
__global__ void kk_gemm_mfma(const float* __restrict__ kk_w, const float* __restrict__ kk_b,
                             const ushort* __restrict__ Bim, int layer,
                             ushort* __restrict__ kern) {
  __shared__ ushort As[128 * KKP];
  __shared__ ushort Bs[128 * KKP];
  __shared__ float bias_s[128];
  int n0 = blockIdx.x * 128;           // 4 col tiles
  int m0 = blockIdx.y * 128;           // 192 row tiles (new-index m)
  int tid = threadIdx.x;
  if (tid < 128) {
    int m = m0 + tid;
    int ks = m >> 13, co = (m & 8191) >> 6, ci = m & 63;
    bias_s[tid] = kk_b[layer * LROWS + ci * 384 + co * 3 + ks];
  }
  const ushort* Bp = Bim + (size_t)n0 * 192;
  int w = tid >> 6, lane = tid & 63, q = lane >> 4, ln = lane & 15;
  int wm = (w >> 1) * 64, wn = (w & 1) * 64;
  f4 acc[4][4] = {};
  for (int kc = 0; kc < 2; kc++) {
    int kbase = kc * 96;
    __syncthreads();
    for (int i = tid; i < 128 * 24; i += 256) {       // A: fp32 -> bf16, permuted rows
      int ml = i / 24, c4 = (i % 24) * 4;
      int m = m0 + ml;
      int ks = m >> 13, co = (m & 8191) >> 6, ci = m & 63;
      int r = ci * 384 + co * 3 + ks;
      float4 v = *(const float4*)(kk_w + ((size_t)layer * LROWS + r) * 192 + kbase + c4);
      us4 o = {f2b(v.x), f2b(v.y), f2b(v.z), f2b(v.w)};
      *(us4*)(&As[ml * KKP + c4]) = o;
    }
    for (int i = tid; i < 128 * 12; i += 256) {       // B: bf16 copy
      int n = i / 12, c8 = (i % 12) * 8;
      us8 v = *(const us8*)(Bp + (size_t)n * 192 + kbase + c8);
      *(us8*)(&Bs[n * KKP + c8]) = v;
    }
    __syncthreads();
    #pragma unroll
    for (int ks = 0; ks < 3; ks++) {
      int kb = ks * 32 + q * 8;
      bh8 af[4], bf[4];
      #pragma unroll
      for (int mi = 0; mi < 4; mi++) af[mi] = *(const bh8*)(&As[(wm + mi * 16 + ln) * KKP + kb]);
      #pragma unroll
      for (int ni = 0; ni < 4; ni++) bf[ni] = *(const bh8*)(&Bs[(wn + ni * 16 + ln) * KKP + kb]);
      #pragma unroll
      for (int mi = 0; mi < 4; mi++)
        #pragma unroll
        for (int ni = 0; ni < 4; ni++) acc[mi][ni] = mfma16(af[mi], bf[ni], acc[mi][ni]);
    }
  }
  // bounce epilogue: coalesced kern stores. Cb[col][m64] (swizzled), 16 KB in As space.
  ushort* Cb = As;
  int myhalf = wm >> 6;
  __syncthreads();
  for (int half = 0; half < 2; half++) {
    if (myhalf == half) {
      #pragma unroll
      for (int mi = 0; mi < 4; mi++) {
        int rloc = wm + mi * 16 + q * 4;
        #pragma unroll
        for (int ni = 0; ni < 4; ni++) {
          int col = wn + ni * 16 + ln;
          #pragma unroll
          for (int r = 0; r < 4; r++) {
            int m64 = (rloc + r) & 63;
            ushort v = f2b(acc[mi][ni][r] + bias_s[rloc + r]);
            Cb[col * 64 + (((m64 >> 3) ^ (col & 7)) * 8) + (m64 & 7)] = v;
          }
        }
      }
    }
    __syncthreads();
    for (int g = tid; g < 1024; g += 256) {
      int col = g >> 3, mc = g & 7;
      us8 v = *(const us8*)(&Cb[col * 64 + ((mc ^ (col & 7)) * 8)]);
      *(us8*)(kern + (size_t)(n0 + col) * LROWS + m0 + half * 64 + mc * 8) = v;
    }
    __syncthreads();
  }
}

// ---------------- dilated conv3 via MFMA (lrelu in, lrelu out) -> yT bf16 ----------------
template <int DIL>
__launch_bounds__(256, 2)
__global__ void conv_mfma(const float* __restrict__ h, const ushort* __restrict__ wct_b,
                          const float* __restrict__ conv_b, int layer, ushort* __restrict__ yT) {
  __shared__ float hs[64][193];        // fp32 window t0-32 .. t0+160, lrelu applied
  __shared__ ushort Bs[192 * 64];      // bf16 transposed [j][ci], xor-chunk swizzled
  int t0 = (blockIdx.x) * 128;
  int b = blockIdx.y;
  int tid = threadIdx.x;
  const float* hb = h + (size_t)b * 64 * OLEN;
  for (int g = tid; g < 64 * 48; g += 256) {
    int ci = g / 48, j4 = (g % 48) * 4;
    int t = t0 - 32 + j4;
    float4 v = make_float4(0.f, 0.f, 0.f, 0.f);
    if (t >= 0 && t < OLEN) v = *(const float4*)(hb + (size_t)ci * OLEN + t);
    hs[ci][j4 + 0] = lrelu(v.x, 0.2f);
    hs[ci][j4 + 1] = lrelu(v.y, 0.2f);
    hs[ci][j4 + 2] = lrelu(v.z, 0.2f);
    hs[ci][j4 + 3] = lrelu(v.w, 0.2f);
  }
  __syncthreads();
  for (int g = tid; g < 192 * 8; g += 256) {
    int j = g >> 3, ch = g & 7;
    us8 o;
    #pragma unroll
    for (int u = 0; u < 8; u++) o[u] = f2b(hs[ch * 8 + u][j]);
    *(us8*)(&Bs[(j * 8 + (ch ^ (j & 7))) * 8]) = o;
  }
  __syncthreads();
  int w = tid >> 6, lane = tid & 63, q = lane >> 4, ln = lane & 15;
  int n0w = w * 32;
  f4 acc[4][2] = {};
  #pragma unroll
  for (int ks = 0; ks < 3; ks++) {
    #pragma unroll
    for (int kst = 0; kst < 2; kst++) {
      bh8 bfr[2];
      #pragma unroll
      for (int nt = 0; nt < 2; nt++) {
        int j = 32 + n0w + nt * 16 + ln + (ks - 1) * DIL;
        bfr[nt] = *(const bh8*)(&Bs[(j * 8 + ((kst * 4 + q) ^ (j & 7))) * 8]);
      }
      #pragma unroll
      for (int mt = 0; mt < 4; mt++) {
        bh8 a = *(const bh8*)(wct_b + (((layer * 3 + ks) * 64) + mt * 16 + ln) * 64 + kst * 32 + q * 8);
        #pragma unroll
        for (int nt = 0; nt < 2; nt++) acc[mt][nt] = mfma16(a, bfr[nt], acc[mt][nt]);
      }
    }
  }
  ushort* yb = (ushort*)hs;
  #pragma unroll
  for (int mt = 0; mt < 4; mt++) {
    #pragma unroll
    for (int r = 0; r < 4; r++) {
      int co = mt * 16 + q * 4 + r;
      float cb = conv_b[layer * 64 + co];
      #pragma unroll
      for (int nt = 0; nt < 2; nt++) {
        int tl = n0w + nt * 16 + ln;
        ushort v = f2b(lrelu(acc[mt][nt][r] + cb, 0.2f));
        yb[(tl * 8 + ((co >> 3) ^ (tl & 7))) * 8 + (co & 7)] = v;
      }
    }
  }
  __syncthreads();
  for (int g = tid; g < 1024; g += 256) {
    int tl = g >> 3, ch = g & 7;
    us8 v = *(const us8*)(&yb[(tl * 8 + (ch ^ (tl & 7))) * 8]);
    *(us8*)(yT + ((size_t)b * YROWS + 32 + t0 + tl) * 64 + ch * 8) = v;
  }
}

// ---------------- LVC (MFMA) + sigmoid*tanh gate, h += ----------------
__launch_bounds__(256, 2)
__global__ void lvc_gate_mfma(const ushort* __restrict__ yT, const ushort* __restrict__ kern,
                              const float* __restrict__ bias_all, int layer,
                              float* __restrict__ h) {
  __shared__ ushort As[LROWS];         // 48 KB: kern slice [ks][co][ci], xor-chunk swizzled
  __shared__ ushort Ys[1040 * 8];      // 16.6 KB: yT rows t0-1 .. t0+128, swizzled
  int sh = blockIdx.x, l = blockIdx.y, b = blockIdx.z;
  int t0 = l * 256 + sh * 128;
  int col = b * 128 + l;
  int tid = threadIdx.x;
  {
    const ushort* kp = kern + (size_t)col * LROWS;
    for (int g = tid; g < 3072; g += 256) {
      us8 v = *(const us8*)(kp + g * 8);
      int co = (g & 1023) >> 3, ch = g & 7;
      *(us8*)(&As[((g & ~7) | (ch ^ (co & 7))) * 8]) = v;
    }
  }
  {
    const ushort* yp = yT + ((size_t)b * YROWS + 32 + t0 - 1) * 64;
    for (int g = tid; g < 1040; g += 256) {
      us8 v = *(const us8*)(yp + g * 8);
      int j = g >> 3, ch = g & 7;
      *(us8*)(&Ys[(j * 8 + (ch ^ (j & 7))) * 8]) = v;
    }
  }
  __syncthreads();
  int w = tid >> 6, lane = tid & 63, q = lane >> 4, ln = lane & 15;
  int n0w = w * 32;
  f4 acc[8][2] = {};
  #pragma unroll
  for (int ks = 0; ks < 3; ks++) {
    #pragma unroll
    for (int kst = 0; kst < 2; kst++) {
      bh8 bfr[2];
      #pragma unroll
      for (int nt = 0; nt < 2; nt++) {
        int j = n0w + nt * 16 + ln + ks;
        bfr[nt] = *(const bh8*)(&Ys[(j * 8 + ((kst * 4 + q) ^ (j & 7))) * 8]);
      }
      #pragma unroll
      for (int mt = 0; mt < 8; mt++) {
        int co = mt * 16 + ln;
        bh8 a = *(const bh8*)(&As[(ks * 1024 + co * 8 + ((kst * 4 + q) ^ (co & 7))) * 8]);
        #pragma unroll
        for (int nt = 0; nt < 2; nt++) acc[mt][nt] = mfma16(a, bfr[nt], acc[mt][nt]);
      }
    }
  }
  float* hb = h + (size_t)b * 64 * OLEN;
  const float* bp = bias_all + (size_t)(b * 512 + layer * 128) * 128 + l;
  #pragma unroll
  for (int mt = 0; mt < 4; mt++) {
    #pragma unroll
    for (int nt = 0; nt < 2; nt++) {
      int t = t0 + n0w + nt * 16 + ln;
      #pragma unroll
      for (int r = 0; r < 4; r++) {
        int co = mt * 16 + q * 4 + r;
        float lo = acc[mt][nt][r] + bp[(size_t)co * 128];
        float hi = acc[mt + 4][nt][r] + bp[(size_t)(co + 64) * 128];
        float sg = 1.f / (1.f + expf(-lo));
        float th = tanhf(hi);
        float* hp = hb + (size_t)co * OLEN + t;
        *hp += sg * th;
      }
    }
  }
}

extern "C" void kernel_launch(void* const* d_in, const int* in_sizes, int n_in,
                              void* d_out, int out_size, void* d_ws, size_t ws_size,
                              hipStream_t stream) {
  const float* x      = (const float*)d_in[0];
  const float* c      = (const float*)d_in[1];
  const float* up_w   = (const float*)d_in[2];
  const float* up_b   = (const float*)d_in[3];
  const float* kin_w  = (const float*)d_in[4];
  const float* kin_b  = (const float*)d_in[5];
  const float* kres_w = (const float*)d_in[6];
  const float* kres_b = (const float*)d_in[7];
  const float* kk_w   = (const float*)d_in[8];
  const float* kk_b   = (const float*)d_in[9];
  const float* kb_w   = (const float*)d_in[10];
  const float* kb_b   = (const float*)d_in[11];
  const float* conv_w = (const float*)d_in[12];
  const float* conv_b = (const float*)d_in[13];
  float* h = (float*)d_out;

  float* ws = (float*)d_ws;
  float* kin_t    = ws; ws += 80 * 5 * 64;
  float* kres_t   = ws; ws += 6 * 64 * 3 * 64;
  float* hsum     = ws; ws += 4 * 64 * 128;
  float* bias_all = ws; ws += 4 * 512 * 128;
  ushort* kern16  = (ushort*)ws; ws += (size_t)512 * LROWS / 2;
  ushort* Bim     = (ushort*)ws; ws += 4 * 128 * 192 / 2;
  ushort* xT      = (ushort*)ws; ws += 4 * 4098 * 64 / 2 + 64;
  ushort* A3      = (ushort*)ws; ws += 512 * 192 / 2;
  ushort* wct_b   = (ushort*)ws; ws += 4 * 3 * 64 * 64 / 2;
  ushort* yT      = (ushort*)ws; ws += (size_t)4 * YROWS * 64 / 2 + 64;

  prep_kernel<<<288, 256, 0, stream>>>(kin_w, kres_w, conv_w, kin_t, kres_t, wct_b);
  prep_up_a<<<384, 256, 0, stream>>>(up_w, A3);
  prep_xt<<<256, 256, 0, stream>>>(x, xT);
  zero_pads<<<8, 256, 0, stream>>>(yT);
  kp_fused<<<dim3(16, 4), 256, 0, stream>>>(c, kin_t, kin_b, kres_t, kres_b, hsum, Bim);
  kb_conv<<<1024, 256, 0, stream>>>(hsum, kb_w, kb_b, bias_all);
  upsample_mfma<<<dim3(128, 4, 4), 256, 0, stream>>>(xT, A3, up_b, h);

  for (int layer = 0; layer < NLAYERS; layer++) {
    kk_gemm_mfma<<<dim3(4, 192), 256, 0, stream>>>(kk_w, kk_b, Bim, layer, kern16);
    switch (layer) {
      case 0: conv_mfma<1><<<dim3(256, 4), 256, 0, stream>>>(h, wct_b, conv_b, layer, yT); break;
      case 1: conv_mfma<3><<<dim3(256, 4), 256, 0, stream>>>(h, wct_b, conv_b, layer, yT); break;
      case 2: conv_mfma<9><<<dim3(256, 4), 256, 0, stream>>>(h, wct_b, conv_b, layer, yT); break;
      case 3: conv_mfma<27><<<dim3(256, 4), 256, 0, stream>>>(h, wct_b, conv_b, layer, yT); break;
    }
    lvc_gate_mfma<<<dim3(2, 128, 4), 256, 0, stream>>>(yT, kern16, bias_all, layer, h);
  }
}

// Round 6
// 580.918 us; speedup vs baseline: 2.9292x; 1.0946x over previous
//
#include <hip/hip_runtime.h>
#include <math.h>

#define CIN 64
#define NLAYERS 4
#define HOP 256
#define ILEN 4096
#define OLEN 32768
#define LROWS 24576   // rows of kk per layer = 64*128*3
#define YROWS 32832   // 32 pad + 32768 + 32 pad

typedef unsigned int uint;
typedef unsigned short ushort;
typedef __attribute__((ext_vector_type(8))) short bh8;
typedef __attribute__((ext_vector_type(4))) float f4;
typedef __attribute__((ext_vector_type(8))) unsigned short us8;
typedef __attribute__((ext_vector_type(4))) unsigned short us4;

__device__ __forceinline__ float lrelu(float x, float s) { return x >= 0.f ? x : s * x; }

__device__ __forceinline__ ushort f2b(float f) {       // fp32 -> bf16 (RNE)
  uint u = __float_as_uint(f);
  u = u + 0x7fff + ((u >> 16) & 1);
  return (ushort)(u >> 16);
}
__device__ __forceinline__ float b2f(ushort u) {
  return __uint_as_float(((uint)u) << 16);
}
__device__ __forceinline__ f4 mfma16(bh8 a, bh8 b, f4 c) {
  return __builtin_amdgcn_mfma_f32_16x16x32_bf16(a, b, c, 0, 0, 0);
}

// ---------------- prep: weight transposes ----------------
// Ah[ch][k=tap*96+cc] bf16 (cc>=80 zero), Ar[j][ch][k=tap*64+ci] bf16, wct_b as before
__global__ void prep_kernel(const float* __restrict__ kin_w, const float* __restrict__ kres_w,
                            const float* __restrict__ conv_w,
                            ushort* __restrict__ Ah, ushort* __restrict__ Ar,
                            ushort* __restrict__ wct_b) {
  int i = blockIdx.x * 256 + threadIdx.x;
  if (i < 64 * 480) {
    int ch = i / 480, k = i % 480, tap = k / 96, cc = k % 96;
    float v = (cc < 80) ? kin_w[(ch * 80 + cc) * 5 + tap] : 0.f;
    Ah[i] = f2b(v);
  }
  if (i < 6 * 64 * 192) {
    int j = i / 12288, r = i % 12288, ch = r / 192, k = r % 192, tap = k >> 6, ci = k & 63;
    Ar[i] = f2b(kres_w[((j * 64 + ch) * 64 + ci) * 3 + tap]);
  }
  if (i < 4 * 3 * 64 * 64) {           // wct_b[l][ks][co][ci] <- bf16(conv_w[l][co][ci][ks])
    int ci = i & 63, r = i >> 6, co = r & 63; r >>= 6; int ks = r % 3, l = r / 3;
    wct_b[i] = f2b(conv_w[((l * 64 + co) * 64 + ci) * 3 + ks]);
  }
}

// zero the 32-row pads of yT (ws is poisoned 0xAA every call)
__global__ void zero_pads(ushort* __restrict__ yT) {
  int i = blockIdx.x * 256 + threadIdx.x;     // 2048 us8 groups
  if (i >= 2048) return;
  int b = i >> 9, rr = i & 511;
  int row = rr >> 3, ch = rr & 7;
  int grow = (row < 32) ? row : (32768 + row);
  us8 z = {0, 0, 0, 0, 0, 0, 0, 0};
  *(us8*)(yT + ((size_t)b * YROWS + grow) * 64 + ch * 8) = z;
}

// A matrix for upsample MFMA: A3[m=co*8+ph][k=(u+1)*64+ci], u = input shift -1/0/+1
__global__ void prep_up_a(const float* __restrict__ up_w, ushort* __restrict__ A3) {
  int i = blockIdx.x * 256 + threadIdx.x;
  if (i >= 512 * 192) return;
  int k = i % 192, m = i / 192;
  int co = m >> 3, ph = m & 7;
  int u = k / 64 - 1, ci = k % 64;
  int kk0 = (11 - ph) & 7;
  int off = (ph < 4) ? -1 : 0;
  int tap = u - off;
  float v = 0.f;
  if (tap == 0 || tap == 1) {
    int a = 15 - kk0 - 8 * tap;
    v = up_w[(ci * 64 + co) * 16 + a];
  }
  A3[i] = f2b(v);
}

// xT[b][1+s][ci] = bf16(lrelu(x[b][ci][s])), rows 0 and 4097 zero-padded
__global__ void prep_xt(const float* __restrict__ x, ushort* __restrict__ xT) {
  __shared__ float ls[64][65];
  int blk = blockIdx.x, b = blk >> 6, st = blk & 63;
  int s0 = st * 64;
  int tid = threadIdx.x;
  int c2 = tid >> 6, s = tid & 63;
  #pragma unroll
  for (int r = 0; r < 16; r++) {
    int ci = r * 4 + c2;
    ls[ci][s] = lrelu(x[((size_t)b * 64 + ci) * ILEN + s0 + s], 0.2f);
  }
  __syncthreads();
  int ci = tid & 63, r2 = tid >> 6;
  #pragma unroll
  for (int r = 0; r < 16; r++) {
    int ss = r * 4 + r2;
    xT[((size_t)b * 4098 + 1 + s0 + ss) * 64 + ci] = f2b(ls[ci][ss]);
  }
  if (st == 0) {
    if (tid < 64) xT[((size_t)b * 4098) * 64 + tid] = 0;
    else if (tid < 128) xT[((size_t)b * 4098 + 4097) * 64 + (tid - 64)] = 0;
  }
}

// ---------------- fused kernel predictor, all-MFMA ----------------
// grid (16 chunks, 4 batch), 512 threads = 8 waves, one 16x16 C-tile each.
// Window n in [0,32) <-> gl = l0-8+n. Head exact on whole window (cT covers gl
// [l0-10,l0+26)); res corruption cascades 1/side/layer -> exact n in [6,26),
// consumed n in [7,17). Activations bf16 in LDS, xor-swizzled (conv_mfma pattern).
__launch_bounds__(512)
__global__ void kp_fused(const float* __restrict__ c, const ushort* __restrict__ Ah,
                         const float* __restrict__ kin_b, const ushort* __restrict__ Ar,
                         const float* __restrict__ kres_b,
                         float* __restrict__ hsum, ushort* __restrict__ Bim) {
  __shared__ ushort cT[36 * 128];   // rows: gl = l0-10+r, 16 chunks of 8 (12 used)
  __shared__ ushort hT[34 * 64];    // head copy, row = n+1
  __shared__ ushort aA[34 * 64];
  __shared__ ushort aB[34 * 64];
  int chunk = blockIdx.x, b = blockIdx.y;
  int l0 = chunk * 8;
  int tid = threadIdx.x;
  us8 z = {0, 0, 0, 0, 0, 0, 0, 0};
  for (int g = tid; g < 576; g += 512) *(us8*)(&cT[g * 8]) = z;
  for (int g = tid; g < 272; g += 512) {
    *(us8*)(&hT[g * 8]) = z; *(us8*)(&aA[g * 8]) = z; *(us8*)(&aB[g * 8]) = z;
  }
  __syncthreads();
  // stage c window
  for (int g = tid; g < 2880; g += 512) {
    int cc = g / 36, r = g % 36;
    int gl = l0 - 10 + r;
    float v = (gl >= 0 && gl < 128) ? c[(b * 80 + cc) * 128 + gl] : 0.f;
    cT[(r * 16 + ((cc >> 3) ^ (r & 7))) * 8 + (cc & 7)] = f2b(v);
  }
  __syncthreads();
  int w = tid >> 6, lane = tid & 63, q = lane >> 4, ln = lane & 15;
  int mt = w >> 1, nt = w & 1;
  int n = nt * 16 + ln;            // output position (C col)
  int m0 = mt * 16;                // ch tile base
  int gl = l0 - 8 + n;
  bool valid = (gl >= 0 && gl < 128);
  // ---- head: 64x32 GEMM, K=480 (15 ksteps) ----
  {
    f4 acc = {0.f, 0.f, 0.f, 0.f};
    #pragma unroll
    for (int s = 0; s < 15; s++) {
      int tap = s / 3;             // wave-uniform
      int chn = (s % 3) * 4 + q;
      bh8 a = *(const bh8*)(Ah + (m0 + ln) * 480 + s * 32 + q * 8);
      int row = n + tap;
      bh8 bf = *(const bh8*)(&cT[(row * 16 + (chn ^ (row & 7))) * 8]);
      acc = mfma16(a, bf, acc);
    }
    us4 o;
    #pragma unroll
    for (int r = 0; r < 4; r++) {
      float v = lrelu(acc[r] + kin_b[m0 + q * 4 + r], 0.1f);
      o[r] = valid ? f2b(v) : (ushort)0;
    }
    int row = n + 1, ch0 = m0 + q * 4;
    int off = (row * 8 + ((ch0 >> 3) ^ (row & 7))) * 8 + (ch0 & 7);
    *(us4*)(&hT[off]) = o;
    *(us4*)(&aA[off]) = o;
  }
  __syncthreads();
  // ---- 6 res layers: 64x32 GEMM, K=192 (6 ksteps) ----
  for (int j = 0; j < 6; j++) {
    const ushort* ain = (j & 1) ? aB : aA;
    ushort* aout_ = (j & 1) ? aA : aB;
    f4 acc = {0.f, 0.f, 0.f, 0.f};
    #pragma unroll
    for (int s = 0; s < 6; s++) {
      int tap = s >> 1;            // wave-uniform
      int chn = (s & 1) * 4 + q;
      bh8 a = *(const bh8*)(Ar + j * 12288 + (m0 + ln) * 192 + s * 32 + q * 8);
      int row = n + tap;
      bh8 bf = *(const bh8*)(&ain[(row * 8 + (chn ^ (row & 7))) * 8]);
      acc = mfma16(a, bf, acc);
    }
    us4 o;
    #pragma unroll
    for (int r = 0; r < 4; r++) {
      float v = lrelu(acc[r] + kres_b[j * 64 + m0 + q * 4 + r], 0.1f);
      o[r] = valid ? f2b(v) : (ushort)0;
    }
    int row = n + 1, ch0 = m0 + q * 4;
    *(us4*)(&aout_[(row * 8 + ((ch0 >> 3) ^ (row & 7))) * 8 + (ch0 & 7)]) = o;
    __syncthreads();
  }
  // ---- final: hsum = head + res6 (in aA), Bim im2col ----
  int tch = tid >> 3, tcl = tid & 7;
  {
    int row = 9 + tcl;             // n = 8+tcl
    int off = (row * 8 + ((tch >> 3) ^ (row & 7))) * 8 + (tch & 7);
    hsum[(b * 64 + tch) * 128 + l0 + tcl] = b2f(hT[off]) + b2f(aA[off]);
  }
  {
    ushort* bp = Bim + ((size_t)(b * 128 + l0 + tcl)) * 192 + tch * 3;
    #pragma unroll
    for (int t = 0; t < 3; t++) {
      int row = 8 + tcl + t;       // n = 7+tcl+t
      int off = (row * 8 + ((tch >> 3) ^ (row & 7))) * 8 + (tch & 7);
      bp[t] = f2b(b2f(hT[off]) + b2f(aA[off]));
    }
  }
}

// ---------------- bias predictor conv3 (64->512) ----------------
__global__ void kb_conv(const float* __restrict__ hsum, const float* __restrict__ kb_w,
                        const float* __restrict__ kb_b, float* __restrict__ bias_all) {
  int i = blockIdx.x * 256 + threadIdx.x;   // over 4*512*128
  int l = i & 127, r = (i >> 7) & 511, b = i >> 16;
  float acc = kb_b[r];
  const float* wp = kb_w + r * 192;
  const float* hp = hsum + b * 64 * 128;
  for (int hid = 0; hid < 64; hid++) {
    #pragma unroll
    for (int t = 0; t < 3; t++) {
      int li = l + t - 1;
      if (li >= 0 && li < 128) acc += hp[hid * 128 + li] * wp[hid * 3 + t];
    }
  }
  bias_all[i] = acc;
}

// ---------------- upsample as MFMA GEMM: M=512 (co*8+ph), N=4096 (s), K=192 ----------------
#define UP_KP 200
__launch_bounds__(256, 2)
__global__ void upsample_mfma(const ushort* __restrict__ xT, const ushort* __restrict__ A3,
                              const float* __restrict__ up_b, float* __restrict__ h) {
  __shared__ ushort As[128 * UP_KP];   // 50 KB
  __shared__ ushort Bs[32 * UP_KP];    // 12.5 KB
  int s0 = blockIdx.x * 32;            // 128 s-tiles
  int m0 = blockIdx.y * 128;           // 4 co-tiles (16 co each)
  int b  = blockIdx.z;
  int tid = threadIdx.x;
  {
    const ushort* src = A3 + (size_t)m0 * 192;
    for (int i = tid; i < 128 * 24; i += 256) {
      int m = i / 24, c8 = (i % 24) * 8;
      us8 v = *(const us8*)(src + (size_t)m * 192 + c8);
      *(us8*)(&As[m * UP_KP + c8]) = v;
    }
  }
  for (int i = tid; i < 32 * 24; i += 256) {
    int n = i / 24, rr = i % 24, u = rr / 8, c8 = (rr % 8) * 8;
    us8 v = *(const us8*)(xT + ((size_t)b * 4098 + s0 + n + u) * 64 + c8);
    *(us8*)(&Bs[n * UP_KP + u * 64 + c8]) = v;
  }
  __syncthreads();
  int w = tid >> 6, lane = tid & 63, q = lane >> 4, ln = lane & 15;
  int wm = w * 32;
  f4 acc[2][2] = {};
  #pragma unroll
  for (int ks = 0; ks < 6; ks++) {
    int kb = ks * 32 + q * 8;
    bh8 a0 = *(const bh8*)(&As[(wm + ln) * UP_KP + kb]);
    bh8 a1 = *(const bh8*)(&As[(wm + 16 + ln) * UP_KP + kb]);
    bh8 b0 = *(const bh8*)(&Bs[ln * UP_KP + kb]);
    bh8 b1 = *(const bh8*)(&Bs[(16 + ln) * UP_KP + kb]);
    acc[0][0] = mfma16(a0, b0, acc[0][0]);
    acc[0][1] = mfma16(a0, b1, acc[0][1]);
    acc[1][0] = mfma16(a1, b0, acc[1][0]);
    acc[1][1] = mfma16(a1, b1, acc[1][1]);
  }
  #pragma unroll
  for (int mi = 0; mi < 2; mi++) {
    int mloc = wm + mi * 16 + q * 4;
    int co = (m0 + mloc) >> 3;
    int ph0 = mloc & 7;
    float bias = up_b[co];
    #pragma unroll
    for (int ni = 0; ni < 2; ni++) {
      int n = s0 + ni * 16 + ln;
      f4 v = acc[mi][ni];
      float4 o = make_float4(v[0] + bias, v[1] + bias, v[2] + bias, v[3] + bias);
      *(float4*)(h + ((size_t)b * 64 + co) * OLEN + n * 8 + ph0) = o;
    }
  }
}

// ---------------- kk GEMM (MFMA), permuted rows m = ks*8192 + co*64 + ci ----------------
#define KKP 104
__launch_bounds__(256, 2)
__global__ void kk_gemm_mfma(const float* __restrict__ kk_w, const float* __restrict__ kk_b,
                             const ushort* __restrict__ Bim, int layer,
                             ushort* __restrict__ kern) {
  __shared__ ushort As[128 * KKP];
  __shared__ ushort Bs[128 * KKP];
  __shared__ float bias_s[128];
  int n0 = blockIdx.x * 128;           // 4 col tiles
  int m0 = blockIdx.y * 128;           // 192 row tiles (new-index m)
  int tid = threadIdx.x;
  if (tid < 128) {
    int m = m0 + tid;
    int ks = m >> 13, co = (m & 8191) >> 6, ci = m & 63;
    bias_s[tid] = kk_b[layer * LROWS + ci * 384 + co * 3 + ks];
  }
  const ushort* Bp = Bim + (size_t)n0 * 192;
  int w = tid >> 6, lane = tid & 63, q = lane >> 4, ln = lane & 15;
  int wm = (w >> 1) * 64, wn = (w & 1) * 64;
  f4 acc[4][4] = {};
  for (int kc = 0; kc < 2; kc++) {
    int kbase = kc * 96;
    __syncthreads();
    for (int i = tid; i < 128 * 24; i += 256) {       // A: fp32 -> bf16, permuted rows
      int ml = i / 24, c4 = (i % 24) * 4;
      int m = m0 + ml;
      int ks = m >> 13, co = (m & 8191) >> 6, ci = m & 63;
      int r = ci * 384 + co * 3 + ks;
      float4 v = *(const float4*)(kk_w + ((size_t)layer * LROWS + r) * 192 + kbase + c4);
      us4 o = {f2b(v.x), f2b(v.y), f2b(v.z), f2b(v.w)};
      *(us4*)(&As[ml * KKP + c4]) = o;
    }
    for (int i = tid; i < 128 * 12; i += 256) {       // B: bf16 copy
      int n = i / 12, c8 = (i % 12) * 8;
      us8 v = *(const us8*)(Bp + (size_t)n * 192 + kbase + c8);
      *(us8*)(&Bs[n * KKP + c8]) = v;
    }
    __syncthreads();
    #pragma unroll
    for (int ks = 0; ks < 3; ks++) {
      int kb = ks * 32 + q * 8;
      bh8 af[4], bf[4];
      #pragma unroll
      for (int mi = 0; mi < 4; mi++) af[mi] = *(const bh8*)(&As[(wm + mi * 16 + ln) * KKP + kb]);
      #pragma unroll
      for (int ni = 0; ni < 4; ni++) bf[ni] = *(const bh8*)(&Bs[(wn + ni * 16 + ln) * KKP + kb]);
      #pragma unroll
      for (int mi = 0; mi < 4; mi++)
        #pragma unroll
        for (int ni = 0; ni < 4; ni++) acc[mi][ni] = mfma16(af[mi], bf[ni], acc[mi][ni]);
    }
  }
  // bounce epilogue: coalesced kern stores. Cb[col][m64] (swizzled), 16 KB in As space.
  ushort* Cb = As;
  int myhalf = wm >> 6;
  __syncthreads();
  for (int half = 0; half < 2; half++) {
    if (myhalf == half) {
      #pragma unroll
      for (int mi = 0; mi < 4; mi++) {
        int rloc = wm + mi * 16 + q * 4;
        #pragma unroll
        for (int ni = 0; ni < 4; ni++) {
          int col = wn + ni * 16 + ln;
          #pragma unroll
          for (int r = 0; r < 4; r++) {
            int m64 = (rloc + r) & 63;
            ushort v = f2b(acc[mi][ni][r] + bias_s[rloc + r]);
            Cb[col * 64 + (((m64 >> 3) ^ (col & 7)) * 8) + (m64 & 7)] = v;
          }
        }
      }
    }
    __syncthreads();
    for (int g = tid; g < 1024; g += 256) {
      int col = g >> 3, mc = g & 7;
      us8 v = *(const us8*)(&Cb[col * 64 + ((mc ^ (col & 7)) * 8)]);
      *(us8*)(kern + (size_t)(n0 + col) * LROWS + m0 + half * 64 + mc * 8) = v;
    }
    __syncthreads();
  }
}

// ---------------- dilated conv3 via MFMA (lrelu in, lrelu out) -> yT bf16 ----------------
template <int DIL>
__launch_bounds__(256, 2)
__global__ void conv_mfma(const float* __restrict__ h, const ushort* __restrict__ wct_b,
                          const float* __restrict__ conv_b, int layer, ushort* __restrict__ yT) {
  __shared__ float hs[64][193];        // fp32 window t0-32 .. t0+160, lrelu applied
  __shared__ ushort Bs[192 * 64];      // bf16 transposed [j][ci], xor-chunk swizzled
  int t0 = (blockIdx.x) * 128;
  int b = blockIdx.y;
  int tid = threadIdx.x;
  const float* hb = h + (size_t)b * 64 * OLEN;
  for (int g = tid; g < 64 * 48; g += 256) {
    int ci = g / 48, j4 = (g % 48) * 4;
    int t = t0 - 32 + j4;
    float4 v = make_float4(0.f, 0.f, 0.f, 0.f);
    if (t >= 0 && t < OLEN) v = *(const float4*)(hb + (size_t)ci * OLEN + t);
    hs[ci][j4 + 0] = lrelu(v.x, 0.2f);
    hs[ci][j4 + 1] = lrelu(v.y, 0.2f);
    hs[ci][j4 + 2] = lrelu(v.z, 0.2f);
    hs[ci][j4 + 3] = lrelu(v.w, 0.2f);
  }
  __syncthreads();
  for (int g = tid; g < 192 * 8; g += 256) {
    int j = g >> 3, ch = g & 7;
    us8 o;
    #pragma unroll
    for (int u = 0; u < 8; u++) o[u] = f2b(hs[ch * 8 + u][j]);
    *(us8*)(&Bs[(j * 8 + (ch ^ (j & 7))) * 8]) = o;
  }
  __syncthreads();
  int w = tid >> 6, lane = tid & 63, q = lane >> 4, ln = lane & 15;
  int n0w = w * 32;
  f4 acc[4][2] = {};
  #pragma unroll
  for (int ks = 0; ks < 3; ks++) {
    #pragma unroll
    for (int kst = 0; kst < 2; kst++) {
      bh8 bfr[2];
      #pragma unroll
      for (int nt = 0; nt < 2; nt++) {
        int j = 32 + n0w + nt * 16 + ln + (ks - 1) * DIL;
        bfr[nt] = *(const bh8*)(&Bs[(j * 8 + ((kst * 4 + q) ^ (j & 7))) * 8]);
      }
      #pragma unroll
      for (int mt = 0; mt < 4; mt++) {
        bh8 a = *(const bh8*)(wct_b + (((layer * 3 + ks) * 64) + mt * 16 + ln) * 64 + kst * 32 + q * 8);
        #pragma unroll
        for (int nt = 0; nt < 2; nt++) acc[mt][nt] = mfma16(a, bfr[nt], acc[mt][nt]);
      }
    }
  }
  ushort* yb = (ushort*)hs;
  #pragma unroll
  for (int mt = 0; mt < 4; mt++) {
    #pragma unroll
    for (int r = 0; r < 4; r++) {
      int co = mt * 16 + q * 4 + r;
      float cb = conv_b[layer * 64 + co];
      #pragma unroll
      for (int nt = 0; nt < 2; nt++) {
        int tl = n0w + nt * 16 + ln;
        ushort v = f2b(lrelu(acc[mt][nt][r] + cb, 0.2f));
        yb[(tl * 8 + ((co >> 3) ^ (tl & 7))) * 8 + (co & 7)] = v;
      }
    }
  }
  __syncthreads();
  for (int g = tid; g < 1024; g += 256) {
    int tl = g >> 3, ch = g & 7;
    us8 v = *(const us8*)(&yb[(tl * 8 + (ch ^ (tl & 7))) * 8]);
    *(us8*)(yT + ((size_t)b * YROWS + 32 + t0 + tl) * 64 + ch * 8) = v;
  }
}

// ---------------- LVC (MFMA) + sigmoid*tanh gate, h += ----------------
__launch_bounds__(256, 2)
__global__ void lvc_gate_mfma(const ushort* __restrict__ yT, const ushort* __restrict__ kern,
                              const float* __restrict__ bias_all, int layer,
                              float* __restrict__ h) {
  __shared__ ushort As[LROWS];         // 48 KB: kern slice [ks][co][ci], xor-chunk swizzled
  __shared__ ushort Ys[1040 * 8];      // 16.6 KB: yT rows t0-1 .. t0+128, swizzled
  int sh = blockIdx.x, l = blockIdx.y, b = blockIdx.z;
  int t0 = l * 256 + sh * 128;
  int col = b * 128 + l;
  int tid = threadIdx.x;
  {
    const ushort* kp = kern + (size_t)col * LROWS;
    for (int g = tid; g < 3072; g += 256) {
      us8 v = *(const us8*)(kp + g * 8);
      int co = (g & 1023) >> 3, ch = g & 7;
      *(us8*)(&As[((g & ~7) | (ch ^ (co & 7))) * 8]) = v;
    }
  }
  {
    const ushort* yp = yT + ((size_t)b * YROWS + 32 + t0 - 1) * 64;
    for (int g = tid; g < 1040; g += 256) {
      us8 v = *(const us8*)(yp + g * 8);
      int j = g >> 3, ch = g & 7;
      *(us8*)(&Ys[(j * 8 + (ch ^ (j & 7))) * 8]) = v;
    }
  }
  __syncthreads();
  int w = tid >> 6, lane = tid & 63, q = lane >> 4, ln = lane & 15;
  int n0w = w * 32;
  f4 acc[8][2] = {};
  #pragma unroll
  for (int ks = 0; ks < 3; ks++) {
    #pragma unroll
    for (int kst = 0; kst < 2; kst++) {
      bh8 bfr[2];
      #pragma unroll
      for (int nt = 0; nt < 2; nt++) {
        int j = n0w + nt * 16 + ln + ks;
        bfr[nt] = *(const bh8*)(&Ys[(j * 8 + ((kst * 4 + q) ^ (j & 7))) * 8]);
      }
      #pragma unroll
      for (int mt = 0; mt < 8; mt++) {
        int co = mt * 16 + ln;
        bh8 a = *(const bh8*)(&As[(ks * 1024 + co * 8 + ((kst * 4 + q) ^ (co & 7))) * 8]);
        #pragma unroll
        for (int nt = 0; nt < 2; nt++) acc[mt][nt] = mfma16(a, bfr[nt], acc[mt][nt]);
      }
    }
  }
  float* hb = h + (size_t)b * 64 * OLEN;
  const float* bp = bias_all + (size_t)(b * 512 + layer * 128) * 128 + l;
  #pragma unroll
  for (int mt = 0; mt < 4; mt++) {
    #pragma unroll
    for (int nt = 0; nt < 2; nt++) {
      int t = t0 + n0w + nt * 16 + ln;
      #pragma unroll
      for (int r = 0; r < 4; r++) {
        int co = mt * 16 + q * 4 + r;
        float lo = acc[mt][nt][r] + bp[(size_t)co * 128];
        float hi = acc[mt + 4][nt][r] + bp[(size_t)(co + 64) * 128];
        float sg = 1.f / (1.f + expf(-lo));
        float th = tanhf(hi);
        float* hp = hb + (size_t)co * OLEN + t;
        *hp += sg * th;
      }
    }
  }
}

extern "C" void kernel_launch(void* const* d_in, const int* in_sizes, int n_in,
                              void* d_out, int out_size, void* d_ws, size_t ws_size,
                              hipStream_t stream) {
  const float* x      = (const float*)d_in[0];
  const float* c      = (const float*)d_in[1];
  const float* up_w   = (const float*)d_in[2];
  const float* up_b   = (const float*)d_in[3];
  const float* kin_w  = (const float*)d_in[4];
  const float* kin_b  = (const float*)d_in[5];
  const float* kres_w = (const float*)d_in[6];
  const float* kres_b = (const float*)d_in[7];
  const float* kk_w   = (const float*)d_in[8];
  const float* kk_b   = (const float*)d_in[9];
  const float* kb_w   = (const float*)d_in[10];
  const float* kb_b   = (const float*)d_in[11];
  const float* conv_w = (const float*)d_in[12];
  const float* conv_b = (const float*)d_in[13];
  float* h = (float*)d_out;

  float* ws = (float*)d_ws;
  float* hsum     = ws; ws += 4 * 64 * 128;
  float* bias_all = ws; ws += 4 * 512 * 128;
  ushort* kern16  = (ushort*)ws; ws += (size_t)512 * LROWS / 2;
  ushort* Bim     = (ushort*)ws; ws += 4 * 128 * 192 / 2;
  ushort* xT      = (ushort*)ws; ws += 4 * 4098 * 64 / 2 + 64;
  ushort* A3      = (ushort*)ws; ws += 512 * 192 / 2;
  ushort* wct_b   = (ushort*)ws; ws += 4 * 3 * 64 * 64 / 2;
  ushort* Ah      = (ushort*)ws; ws += 64 * 480 / 2;
  ushort* Ar      = (ushort*)ws; ws += 6 * 64 * 192 / 2;
  ushort* yT      = (ushort*)ws; ws += (size_t)4 * YROWS * 64 / 2 + 64;

  prep_kernel<<<288, 256, 0, stream>>>(kin_w, kres_w, conv_w, Ah, Ar, wct_b);
  prep_up_a<<<384, 256, 0, stream>>>(up_w, A3);
  prep_xt<<<256, 256, 0, stream>>>(x, xT);
  zero_pads<<<8, 256, 0, stream>>>(yT);
  kp_fused<<<dim3(16, 4), 512, 0, stream>>>(c, Ah, kin_b, Ar, kres_b, hsum, Bim);
  kb_conv<<<1024, 256, 0, stream>>>(hsum, kb_w, kb_b, bias_all);
  upsample_mfma<<<dim3(128, 4, 4), 256, 0, stream>>>(xT, A3, up_b, h);

  for (int layer = 0; layer < NLAYERS; layer++) {
    kk_gemm_mfma<<<dim3(4, 192), 256, 0, stream>>>(kk_w, kk_b, Bim, layer, kern16);
    switch (layer) {
      case 0: conv_mfma<1><<<dim3(256, 4), 256, 0, stream>>>(h, wct_b, conv_b, layer, yT); break;
      case 1: conv_mfma<3><<<dim3(256, 4), 256, 0, stream>>>(h, wct_b, conv_b, layer, yT); break;
      case 2: conv_mfma<9><<<dim3(256, 4), 256, 0, stream>>>(h, wct_b, conv_b, layer, yT); break;
      case 3: conv_mfma<27><<<dim3(256, 4), 256, 0, stream>>>(h, wct_b, conv_b, layer, yT); break;
    }
    lvc_gate_mfma<<<dim3(2, 128, 4), 256, 0, stream>>>(yT, kern16, bias_all, layer, h);
  }
}

// Round 7
// 522.176 us; speedup vs baseline: 3.2587x; 1.1125x over previous
//
#include <hip/hip_runtime.h>
#include <math.h>

#define CIN 64
#define NLAYERS 4
#define HOP 256
#define ILEN 4096
#define OLEN 32768
#define LROWS 24576   // rows of kk per layer = 64*128*3
#define YROWS 32832   // 32 pad + 32768 + 32 pad

typedef unsigned int uint;
typedef unsigned short ushort;
typedef __attribute__((ext_vector_type(8))) short bh8;
typedef __attribute__((ext_vector_type(4))) float f4;
typedef __attribute__((ext_vector_type(8))) unsigned short us8;
typedef __attribute__((ext_vector_type(4))) unsigned short us4;

__device__ __forceinline__ float lrelu(float x, float s) { return x >= 0.f ? x : s * x; }

__device__ __forceinline__ ushort f2b(float f) {       // fp32 -> bf16 (RNE)
  uint u = __float_as_uint(f);
  u = u + 0x7fff + ((u >> 16) & 1);
  return (ushort)(u >> 16);
}
__device__ __forceinline__ float b2f(ushort u) {
  return __uint_as_float(((uint)u) << 16);
}
__device__ __forceinline__ f4 mfma16(bh8 a, bh8 b, f4 c) {
  return __builtin_amdgcn_mfma_f32_16x16x32_bf16(a, b, c, 0, 0, 0);
}

// ---------------- mega prep: all weight transposes + xT + yT pads, one launch ------------
// blocks [0,288): Ah/Ar/wct_b; [288,672): A3; [672,680): yT pads; [680,936): xT
__global__ void mega_prep(const float* __restrict__ kin_w, const float* __restrict__ kres_w,
                          const float* __restrict__ conv_w, const float* __restrict__ up_w,
                          const float* __restrict__ x,
                          ushort* __restrict__ Ah, ushort* __restrict__ Ar,
                          ushort* __restrict__ wct_b, ushort* __restrict__ A3,
                          ushort* __restrict__ xT, ushort* __restrict__ yT) {
  __shared__ float ls[64][65];
  int bid = blockIdx.x, tid = threadIdx.x;
  if (bid < 288) {
    int i = bid * 256 + tid;
    if (i < 64 * 480) {
      int ch = i / 480, k = i % 480, tap = k / 96, cc = k % 96;
      float v = (cc < 80) ? kin_w[(ch * 80 + cc) * 5 + tap] : 0.f;
      Ah[i] = f2b(v);
    }
    if (i < 6 * 64 * 192) {
      int j = i / 12288, r = i % 12288, ch = r / 192, k = r % 192, tap = k >> 6, ci = k & 63;
      Ar[i] = f2b(kres_w[((j * 64 + ch) * 64 + ci) * 3 + tap]);
    }
    if (i < 4 * 3 * 64 * 64) {         // wct_b[l][ks][co][ci]
      int ci = i & 63, r = i >> 6, co = r & 63; r >>= 6; int ks = r % 3, l = r / 3;
      wct_b[i] = f2b(conv_w[((l * 64 + co) * 64 + ci) * 3 + ks]);
    }
  } else if (bid < 672) {
    int i = (bid - 288) * 256 + tid;   // A3[m=co*8+ph][k=(u+1)*64+ci]
    if (i < 512 * 192) {
      int k = i % 192, m = i / 192;
      int co = m >> 3, ph = m & 7;
      int u = k / 64 - 1, ci = k % 64;
      int kk0 = (11 - ph) & 7;
      int off = (ph < 4) ? -1 : 0;
      int tap = u - off;
      float v = 0.f;
      if (tap == 0 || tap == 1) {
        int a = 15 - kk0 - 8 * tap;
        v = up_w[(ci * 64 + co) * 16 + a];
      }
      A3[i] = f2b(v);
    }
  } else if (bid < 680) {
    int i = (bid - 672) * 256 + tid;   // zero yT pads
    if (i < 2048) {
      int b = i >> 9, rr = i & 511;
      int row = rr >> 3, ch = rr & 7;
      int grow = (row < 32) ? row : (32768 + row);
      us8 z = {0, 0, 0, 0, 0, 0, 0, 0};
      *(us8*)(yT + ((size_t)b * YROWS + grow) * 64 + ch * 8) = z;
    }
  } else {
    int blk = bid - 680, b = blk >> 6, st = blk & 63;   // xT
    int s0 = st * 64;
    int c2 = tid >> 6, s = tid & 63;
    #pragma unroll
    for (int r = 0; r < 16; r++) {
      int ci = r * 4 + c2;
      ls[ci][s] = lrelu(x[((size_t)b * 64 + ci) * ILEN + s0 + s], 0.2f);
    }
    __syncthreads();
    int ci = tid & 63, r2 = tid >> 6;
    #pragma unroll
    for (int r = 0; r < 16; r++) {
      int ss = r * 4 + r2;
      xT[((size_t)b * 4098 + 1 + s0 + ss) * 64 + ci] = f2b(ls[ci][ss]);
    }
    if (st == 0) {
      if (tid < 64) xT[((size_t)b * 4098) * 64 + tid] = 0;
      else if (tid < 128) xT[((size_t)b * 4098 + 4097) * 64 + (tid - 64)] = 0;
    }
  }
}

// ---------------- fused kernel predictor, all-MFMA (unchanged from R5) ----------------
__launch_bounds__(512)
__global__ void kp_fused(const float* __restrict__ c, const ushort* __restrict__ Ah,
                         const float* __restrict__ kin_b, const ushort* __restrict__ Ar,
                         const float* __restrict__ kres_b,
                         float* __restrict__ hsum, ushort* __restrict__ Bim) {
  __shared__ ushort cT[36 * 128];
  __shared__ ushort hT[34 * 64];
  __shared__ ushort aA[34 * 64];
  __shared__ ushort aB[34 * 64];
  int chunk = blockIdx.x, b = blockIdx.y;
  int l0 = chunk * 8;
  int tid = threadIdx.x;
  us8 z = {0, 0, 0, 0, 0, 0, 0, 0};
  for (int g = tid; g < 576; g += 512) *(us8*)(&cT[g * 8]) = z;
  for (int g = tid; g < 272; g += 512) {
    *(us8*)(&hT[g * 8]) = z; *(us8*)(&aA[g * 8]) = z; *(us8*)(&aB[g * 8]) = z;
  }
  __syncthreads();
  for (int g = tid; g < 2880; g += 512) {
    int cc = g / 36, r = g % 36;
    int gl = l0 - 10 + r;
    float v = (gl >= 0 && gl < 128) ? c[(b * 80 + cc) * 128 + gl] : 0.f;
    cT[(r * 16 + ((cc >> 3) ^ (r & 7))) * 8 + (cc & 7)] = f2b(v);
  }
  __syncthreads();
  int w = tid >> 6, lane = tid & 63, q = lane >> 4, ln = lane & 15;
  int mt = w >> 1, nt = w & 1;
  int n = nt * 16 + ln;
  int m0 = mt * 16;
  int gl = l0 - 8 + n;
  bool valid = (gl >= 0 && gl < 128);
  {
    f4 acc = {0.f, 0.f, 0.f, 0.f};
    #pragma unroll
    for (int s = 0; s < 15; s++) {
      int tap = s / 3;
      int chn = (s % 3) * 4 + q;
      bh8 a = *(const bh8*)(Ah + (m0 + ln) * 480 + s * 32 + q * 8);
      int row = n + tap;
      bh8 bf = *(const bh8*)(&cT[(row * 16 + (chn ^ (row & 7))) * 8]);
      acc = mfma16(a, bf, acc);
    }
    us4 o;
    #pragma unroll
    for (int r = 0; r < 4; r++) {
      float v = lrelu(acc[r] + kin_b[m0 + q * 4 + r], 0.1f);
      o[r] = valid ? f2b(v) : (ushort)0;
    }
    int row = n + 1, ch0 = m0 + q * 4;
    int off = (row * 8 + ((ch0 >> 3) ^ (row & 7))) * 8 + (ch0 & 7);
    *(us4*)(&hT[off]) = o;
    *(us4*)(&aA[off]) = o;
  }
  __syncthreads();
  for (int j = 0; j < 6; j++) {
    const ushort* ain = (j & 1) ? aB : aA;
    ushort* aout_ = (j & 1) ? aA : aB;
    f4 acc = {0.f, 0.f, 0.f, 0.f};
    #pragma unroll
    for (int s = 0; s < 6; s++) {
      int tap = s >> 1;
      int chn = (s & 1) * 4 + q;
      bh8 a = *(const bh8*)(Ar + j * 12288 + (m0 + ln) * 192 + s * 32 + q * 8);
      int row = n + tap;
      bh8 bf = *(const bh8*)(&ain[(row * 8 + (chn ^ (row & 7))) * 8]);
      acc = mfma16(a, bf, acc);
    }
    us4 o;
    #pragma unroll
    for (int r = 0; r < 4; r++) {
      float v = lrelu(acc[r] + kres_b[j * 64 + m0 + q * 4 + r], 0.1f);
      o[r] = valid ? f2b(v) : (ushort)0;
    }
    int row = n + 1, ch0 = m0 + q * 4;
    *(us4*)(&aout_[(row * 8 + ((ch0 >> 3) ^ (row & 7))) * 8 + (ch0 & 7)]) = o;
    __syncthreads();
  }
  int tch = tid >> 3, tcl = tid & 7;
  {
    int row = 9 + tcl;
    int off = (row * 8 + ((tch >> 3) ^ (row & 7))) * 8 + (tch & 7);
    hsum[(b * 64 + tch) * 128 + l0 + tcl] = b2f(hT[off]) + b2f(aA[off]);
  }
  {
    ushort* bp = Bim + ((size_t)(b * 128 + l0 + tcl)) * 192 + tch * 3;
    #pragma unroll
    for (int t = 0; t < 3; t++) {
      int row = 8 + tcl + t;
      int off = (row * 8 + ((tch >> 3) ^ (row & 7))) * 8 + (tch & 7);
      bp[t] = f2b(b2f(hT[off]) + b2f(aA[off]));
    }
  }
}

#define KKP 104

// ---------------- bias predictor as MFMA GEMM: M=512 (r), N=512 (b*128+l), K=192 -------
__launch_bounds__(256)
__global__ void kb_mfma(const float* __restrict__ kb_w, const float* __restrict__ kb_b,
                        const ushort* __restrict__ Bim, float* __restrict__ bias_all) {
  __shared__ ushort As[128 * KKP];
  __shared__ ushort Bs[128 * KKP];
  __shared__ float bias_s[128];
  int n0 = blockIdx.x * 128;
  int m0 = blockIdx.y * 128;
  int tid = threadIdx.x;
  if (tid < 128) bias_s[tid] = kb_b[m0 + tid];
  const ushort* Bp = Bim + (size_t)n0 * 192;
  int w = tid >> 6, lane = tid & 63, q = lane >> 4, ln = lane & 15;
  int wm = (w >> 1) * 64, wn = (w & 1) * 64;
  f4 acc[4][4] = {};
  for (int kc = 0; kc < 2; kc++) {
    int kbase = kc * 96;
    __syncthreads();
    for (int i = tid; i < 128 * 24; i += 256) {
      int ml = i / 24, c4 = (i % 24) * 4;
      float4 v = *(const float4*)(kb_w + (size_t)(m0 + ml) * 192 + kbase + c4);
      us4 o = {f2b(v.x), f2b(v.y), f2b(v.z), f2b(v.w)};
      *(us4*)(&As[ml * KKP + c4]) = o;
    }
    for (int i = tid; i < 128 * 12; i += 256) {
      int n = i / 12, c8 = (i % 12) * 8;
      us8 v = *(const us8*)(Bp + (size_t)n * 192 + kbase + c8);
      *(us8*)(&Bs[n * KKP + c8]) = v;
    }
    __syncthreads();
    #pragma unroll
    for (int ks = 0; ks < 3; ks++) {
      int kb = ks * 32 + q * 8;
      bh8 af[4], bf[4];
      #pragma unroll
      for (int mi = 0; mi < 4; mi++) af[mi] = *(const bh8*)(&As[(wm + mi * 16 + ln) * KKP + kb]);
      #pragma unroll
      for (int ni = 0; ni < 4; ni++) bf[ni] = *(const bh8*)(&Bs[(wn + ni * 16 + ln) * KKP + kb]);
      #pragma unroll
      for (int mi = 0; mi < 4; mi++)
        #pragma unroll
        for (int ni = 0; ni < 4; ni++) acc[mi][ni] = mfma16(af[mi], bf[ni], acc[mi][ni]);
    }
  }
  #pragma unroll
  for (int mi = 0; mi < 4; mi++) {
    #pragma unroll
    for (int ni = 0; ni < 4; ni++) {
      int col = n0 + wn + ni * 16 + ln;
      int b = col >> 7, l = col & 127;
      #pragma unroll
      for (int r = 0; r < 4; r++) {
        int rloc = wm + mi * 16 + q * 4 + r;
        bias_all[((size_t)(b * 512 + m0 + rloc)) * 128 + l] = acc[mi][ni][r] + bias_s[rloc];
      }
    }
  }
}

// ---------------- upsample as MFMA GEMM (unchanged) ----------------
#define UP_KP 200
__launch_bounds__(256, 2)
__global__ void upsample_mfma(const ushort* __restrict__ xT, const ushort* __restrict__ A3,
                              const float* __restrict__ up_b, float* __restrict__ h) {
  __shared__ ushort As[128 * UP_KP];
  __shared__ ushort Bs[32 * UP_KP];
  int s0 = blockIdx.x * 32;
  int m0 = blockIdx.y * 128;
  int b  = blockIdx.z;
  int tid = threadIdx.x;
  {
    const ushort* src = A3 + (size_t)m0 * 192;
    for (int i = tid; i < 128 * 24; i += 256) {
      int m = i / 24, c8 = (i % 24) * 8;
      us8 v = *(const us8*)(src + (size_t)m * 192 + c8);
      *(us8*)(&As[m * UP_KP + c8]) = v;
    }
  }
  for (int i = tid; i < 32 * 24; i += 256) {
    int n = i / 24, rr = i % 24, u = rr / 8, c8 = (rr % 8) * 8;
    us8 v = *(const us8*)(xT + ((size_t)b * 4098 + s0 + n + u) * 64 + c8);
    *(us8*)(&Bs[n * UP_KP + u * 64 + c8]) = v;
  }
  __syncthreads();
  int w = tid >> 6, lane = tid & 63, q = lane >> 4, ln = lane & 15;
  int wm = w * 32;
  f4 acc[2][2] = {};
  #pragma unroll
  for (int ks = 0; ks < 6; ks++) {
    int kb = ks * 32 + q * 8;
    bh8 a0 = *(const bh8*)(&As[(wm + ln) * UP_KP + kb]);
    bh8 a1 = *(const bh8*)(&As[(wm + 16 + ln) * UP_KP + kb]);
    bh8 b0 = *(const bh8*)(&Bs[ln * UP_KP + kb]);
    bh8 b1 = *(const bh8*)(&Bs[(16 + ln) * UP_KP + kb]);
    acc[0][0] = mfma16(a0, b0, acc[0][0]);
    acc[0][1] = mfma16(a0, b1, acc[0][1]);
    acc[1][0] = mfma16(a1, b0, acc[1][0]);
    acc[1][1] = mfma16(a1, b1, acc[1][1]);
  }
  #pragma unroll
  for (int mi = 0; mi < 2; mi++) {
    int mloc = wm + mi * 16 + q * 4;
    int co = (m0 + mloc) >> 3;
    int ph0 = mloc & 7;
    float bias = up_b[co];
    #pragma unroll
    for (int ni = 0; ni < 2; ni++) {
      int n = s0 + ni * 16 + ln;
      f4 v = acc[mi][ni];
      float4 o = make_float4(v[0] + bias, v[1] + bias, v[2] + bias, v[3] + bias);
      *(float4*)(h + ((size_t)b * 64 + co) * OLEN + n * 8 + ph0) = o;
    }
  }
}

// ---------------- kk GEMM (MFMA), all 4 layers in one dispatch (z = layer) -------------
__launch_bounds__(256, 2)
__global__ void kk_gemm_mfma(const float* __restrict__ kk_w, const float* __restrict__ kk_b,
                             const ushort* __restrict__ Bim, ushort* __restrict__ kern4) {
  __shared__ ushort As[128 * KKP];
  __shared__ ushort Bs[128 * KKP];
  __shared__ float bias_s[128];
  int n0 = blockIdx.x * 128;
  int m0 = blockIdx.y * 128;
  int layer = blockIdx.z;
  int tid = threadIdx.x;
  if (tid < 128) {
    int m = m0 + tid;
    int ks = m >> 13, co = (m & 8191) >> 6, ci = m & 63;
    bias_s[tid] = kk_b[layer * LROWS + ci * 384 + co * 3 + ks];
  }
  const ushort* Bp = Bim + (size_t)n0 * 192;
  int w = tid >> 6, lane = tid & 63, q = lane >> 4, ln = lane & 15;
  int wm = (w >> 1) * 64, wn = (w & 1) * 64;
  f4 acc[4][4] = {};
  for (int kc = 0; kc < 2; kc++) {
    int kbase = kc * 96;
    __syncthreads();
    for (int i = tid; i < 128 * 24; i += 256) {
      int ml = i / 24, c4 = (i % 24) * 4;
      int m = m0 + ml;
      int ks = m >> 13, co = (m & 8191) >> 6, ci = m & 63;
      int r = ci * 384 + co * 3 + ks;
      float4 v = *(const float4*)(kk_w + ((size_t)layer * LROWS + r) * 192 + kbase + c4);
      us4 o = {f2b(v.x), f2b(v.y), f2b(v.z), f2b(v.w)};
      *(us4*)(&As[ml * KKP + c4]) = o;
    }
    for (int i = tid; i < 128 * 12; i += 256) {
      int n = i / 12, c8 = (i % 12) * 8;
      us8 v = *(const us8*)(Bp + (size_t)n * 192 + kbase + c8);
      *(us8*)(&Bs[n * KKP + c8]) = v;
    }
    __syncthreads();
    #pragma unroll
    for (int ks = 0; ks < 3; ks++) {
      int kb = ks * 32 + q * 8;
      bh8 af[4], bf[4];
      #pragma unroll
      for (int mi = 0; mi < 4; mi++) af[mi] = *(const bh8*)(&As[(wm + mi * 16 + ln) * KKP + kb]);
      #pragma unroll
      for (int ni = 0; ni < 4; ni++) bf[ni] = *(const bh8*)(&Bs[(wn + ni * 16 + ln) * KKP + kb]);
      #pragma unroll
      for (int mi = 0; mi < 4; mi++)
        #pragma unroll
        for (int ni = 0; ni < 4; ni++) acc[mi][ni] = mfma16(af[mi], bf[ni], acc[mi][ni]);
    }
  }
  ushort* Cb = As;
  int myhalf = wm >> 6;
  __syncthreads();
  for (int half = 0; half < 2; half++) {
    if (myhalf == half) {
      #pragma unroll
      for (int mi = 0; mi < 4; mi++) {
        int rloc = wm + mi * 16 + q * 4;
        #pragma unroll
        for (int ni = 0; ni < 4; ni++) {
          int col = wn + ni * 16 + ln;
          #pragma unroll
          for (int r = 0; r < 4; r++) {
            int m64 = (rloc + r) & 63;
            ushort v = f2b(acc[mi][ni][r] + bias_s[rloc + r]);
            Cb[col * 64 + (((m64 >> 3) ^ (col & 7)) * 8) + (m64 & 7)] = v;
          }
        }
      }
    }
    __syncthreads();
    for (int g = tid; g < 1024; g += 256) {
      int col = g >> 3, mc = g & 7;
      us8 v = *(const us8*)(&Cb[col * 64 + ((mc ^ (col & 7)) * 8)]);
      *(us8*)(kern4 + ((size_t)layer * 512 + n0 + col) * LROWS + m0 + half * 64 + mc * 8) = v;
    }
    __syncthreads();
  }
}

// ---------------- dilated conv3 via MFMA, bf16 h-window (50 KB LDS, 3 blocks/CU) -------
template <int DIL>
__launch_bounds__(256, 3)
__global__ void conv_mfma(const float* __restrict__ h, const ushort* __restrict__ wct_b,
                          const float* __restrict__ conv_b, int layer, ushort* __restrict__ yT) {
  __shared__ ushort hsb[64 * 196];     // bf16 lrelu'd window t0-32 .. t0+160
  __shared__ ushort Bs[192 * 64];      // transposed [j][ci], xor-chunk swizzled
  int t0 = (blockIdx.x) * 128;
  int b = blockIdx.y;
  int tid = threadIdx.x;
  const float* hb = h + (size_t)b * 64 * OLEN;
  for (int g = tid; g < 64 * 48; g += 256) {
    int ci = g / 48, j4 = (g % 48) * 4;
    int t = t0 - 32 + j4;
    float4 v = make_float4(0.f, 0.f, 0.f, 0.f);
    if (t >= 0 && t < OLEN) v = *(const float4*)(hb + (size_t)ci * OLEN + t);
    us4 o = {f2b(lrelu(v.x, 0.2f)), f2b(lrelu(v.y, 0.2f)),
             f2b(lrelu(v.z, 0.2f)), f2b(lrelu(v.w, 0.2f))};
    *(us4*)(&hsb[ci * 196 + j4]) = o;
  }
  __syncthreads();
  for (int g = tid; g < 192 * 8; g += 256) {
    int j = g >> 3, ch = g & 7;
    us8 o;
    #pragma unroll
    for (int u = 0; u < 8; u++) o[u] = hsb[(ch * 8 + u) * 196 + j];
    *(us8*)(&Bs[(j * 8 + (ch ^ (j & 7))) * 8]) = o;
  }
  __syncthreads();
  int w = tid >> 6, lane = tid & 63, q = lane >> 4, ln = lane & 15;
  int n0w = w * 32;
  f4 acc[4][2] = {};
  #pragma unroll
  for (int ks = 0; ks < 3; ks++) {
    #pragma unroll
    for (int kst = 0; kst < 2; kst++) {
      bh8 bfr[2];
      #pragma unroll
      for (int nt = 0; nt < 2; nt++) {
        int j = 32 + n0w + nt * 16 + ln + (ks - 1) * DIL;
        bfr[nt] = *(const bh8*)(&Bs[(j * 8 + ((kst * 4 + q) ^ (j & 7))) * 8]);
      }
      #pragma unroll
      for (int mt = 0; mt < 4; mt++) {
        bh8 a = *(const bh8*)(wct_b + (((layer * 3 + ks) * 64) + mt * 16 + ln) * 64 + kst * 32 + q * 8);
        #pragma unroll
        for (int nt = 0; nt < 2; nt++) acc[mt][nt] = mfma16(a, bfr[nt], acc[mt][nt]);
      }
    }
  }
  __syncthreads();                     // Bs reads done before aliasing as bounce buffer
  ushort* yb = Bs;
  #pragma unroll
  for (int mt = 0; mt < 4; mt++) {
    #pragma unroll
    for (int r = 0; r < 4; r++) {
      int co = mt * 16 + q * 4 + r;
      float cb = conv_b[layer * 64 + co];
      #pragma unroll
      for (int nt = 0; nt < 2; nt++) {
        int tl = n0w + nt * 16 + ln;
        ushort v = f2b(lrelu(acc[mt][nt][r] + cb, 0.2f));
        yb[(tl * 8 + ((co >> 3) ^ (tl & 7))) * 8 + (co & 7)] = v;
      }
    }
  }
  __syncthreads();
  for (int g = tid; g < 1024; g += 256) {
    int tl = g >> 3, ch = g & 7;
    us8 v = *(const us8*)(&yb[(tl * 8 + (ch ^ (tl & 7))) * 8]);
    *(us8*)(yT + ((size_t)b * YROWS + 32 + t0 + tl) * 64 + ch * 8) = v;
  }
}

// ---------------- LVC (MFMA) + gate, per-ks kern chunking (33 KB LDS) ----------------
__launch_bounds__(256, 3)
__global__ void lvc_gate_mfma(const ushort* __restrict__ yT, const ushort* __restrict__ kern4,
                              const float* __restrict__ bias_all, int layer,
                              float* __restrict__ h) {
  __shared__ ushort As[8192];          // 16 KB: kern ks-chunk [co][ci], swizzled
  __shared__ ushort Ys[1040 * 8];      // 16.6 KB
  int sh = blockIdx.x, l = blockIdx.y, b = blockIdx.z;
  int t0 = l * 256 + sh * 128;
  int col = b * 128 + l;
  int tid = threadIdx.x;
  const ushort* kp = kern4 + ((size_t)layer * 512 + col) * LROWS;
  {
    const ushort* yp = yT + ((size_t)b * YROWS + 32 + t0 - 1) * 64;
    for (int g = tid; g < 1040; g += 256) {
      us8 v = *(const us8*)(yp + g * 8);
      int j = g >> 3, ch = g & 7;
      *(us8*)(&Ys[(j * 8 + (ch ^ (j & 7))) * 8]) = v;
    }
  }
  int w = tid >> 6, lane = tid & 63, q = lane >> 4, ln = lane & 15;
  int n0w = w * 32;
  f4 acc[8][2] = {};
  for (int ks = 0; ks < 3; ks++) {
    __syncthreads();                   // covers Ys (first iter) + As reuse (later iters)
    for (int g = tid; g < 1024; g += 256) {
      us8 v = *(const us8*)(kp + ks * 8192 + g * 8);
      int co = g >> 3, ch = g & 7;
      *(us8*)(&As[((g & ~7) | (ch ^ (co & 7))) * 8]) = v;
    }
    __syncthreads();
    #pragma unroll
    for (int kst = 0; kst < 2; kst++) {
      bh8 bfr[2];
      #pragma unroll
      for (int nt = 0; nt < 2; nt++) {
        int j = n0w + nt * 16 + ln + ks;
        bfr[nt] = *(const bh8*)(&Ys[(j * 8 + ((kst * 4 + q) ^ (j & 7))) * 8]);
      }
      #pragma unroll
      for (int mt = 0; mt < 8; mt++) {
        int co = mt * 16 + ln;
        bh8 a = *(const bh8*)(&As[(co * 8 + ((kst * 4 + q) ^ (co & 7))) * 8]);
        #pragma unroll
        for (int nt = 0; nt < 2; nt++) acc[mt][nt] = mfma16(a, bfr[nt], acc[mt][nt]);
      }
    }
  }
  float* hb = h + (size_t)b * 64 * OLEN;
  const float* bp = bias_all + (size_t)(b * 512 + layer * 128) * 128 + l;
  #pragma unroll
  for (int mt = 0; mt < 4; mt++) {
    #pragma unroll
    for (int nt = 0; nt < 2; nt++) {
      int t = t0 + n0w + nt * 16 + ln;
      #pragma unroll
      for (int r = 0; r < 4; r++) {
        int co = mt * 16 + q * 4 + r;
        float lo = acc[mt][nt][r] + bp[(size_t)co * 128];
        float hi = acc[mt + 4][nt][r] + bp[(size_t)(co + 64) * 128];
        float sg = 1.f / (1.f + expf(-lo));
        float th = tanhf(hi);
        float* hp = hb + (size_t)co * OLEN + t;
        *hp += sg * th;
      }
    }
  }
}

extern "C" void kernel_launch(void* const* d_in, const int* in_sizes, int n_in,
                              void* d_out, int out_size, void* d_ws, size_t ws_size,
                              hipStream_t stream) {
  const float* x      = (const float*)d_in[0];
  const float* c      = (const float*)d_in[1];
  const float* up_w   = (const float*)d_in[2];
  const float* up_b   = (const float*)d_in[3];
  const float* kin_w  = (const float*)d_in[4];
  const float* kin_b  = (const float*)d_in[5];
  const float* kres_w = (const float*)d_in[6];
  const float* kres_b = (const float*)d_in[7];
  const float* kk_w   = (const float*)d_in[8];
  const float* kk_b   = (const float*)d_in[9];
  const float* kb_w   = (const float*)d_in[10];
  const float* kb_b   = (const float*)d_in[11];
  const float* conv_w = (const float*)d_in[12];
  const float* conv_b = (const float*)d_in[13];
  float* h = (float*)d_out;

  float* ws = (float*)d_ws;
  float* hsum     = ws; ws += 4 * 64 * 128;
  float* bias_all = ws; ws += 4 * 512 * 128;
  ushort* kern4   = (ushort*)ws; ws += (size_t)4 * 512 * LROWS / 2;
  ushort* Bim     = (ushort*)ws; ws += 4 * 128 * 192 / 2;
  ushort* xT      = (ushort*)ws; ws += 4 * 4098 * 64 / 2 + 64;
  ushort* A3      = (ushort*)ws; ws += 512 * 192 / 2;
  ushort* wct_b   = (ushort*)ws; ws += 4 * 3 * 64 * 64 / 2;
  ushort* Ah      = (ushort*)ws; ws += 64 * 480 / 2;
  ushort* Ar      = (ushort*)ws; ws += 6 * 64 * 192 / 2;
  ushort* yT      = (ushort*)ws; ws += (size_t)4 * YROWS * 64 / 2 + 64;

  mega_prep<<<936, 256, 0, stream>>>(kin_w, kres_w, conv_w, up_w, x, Ah, Ar, wct_b, A3, xT, yT);
  kp_fused<<<dim3(16, 4), 512, 0, stream>>>(c, Ah, kin_b, Ar, kres_b, hsum, Bim);
  kb_mfma<<<dim3(4, 4), 256, 0, stream>>>(kb_w, kb_b, Bim, bias_all);
  kk_gemm_mfma<<<dim3(4, 192, 4), 256, 0, stream>>>(kk_w, kk_b, Bim, kern4);
  upsample_mfma<<<dim3(128, 4, 4), 256, 0, stream>>>(xT, A3, up_b, h);

  for (int layer = 0; layer < NLAYERS; layer++) {
    switch (layer) {
      case 0: conv_mfma<1><<<dim3(256, 4), 256, 0, stream>>>(h, wct_b, conv_b, layer, yT); break;
      case 1: conv_mfma<3><<<dim3(256, 4), 256, 0, stream>>>(h, wct_b, conv_b, layer, yT); break;
      case 2: conv_mfma<9><<<dim3(256, 4), 256, 0, stream>>>(h, wct_b, conv_b, layer, yT); break;
      case 3: conv_mfma<27><<<dim3(256, 4), 256, 0, stream>>>(h, wct_b, conv_b, layer, yT); break;
    }
    lvc_gate_mfma<<<dim3(2, 128, 4), 256, 0, stream>>>(yT, kern4, bias_all, layer, h);
  }
}